// Round 1
// baseline (987.406 us; speedup 1.0000x reference)
//
#include <hip/hip_runtime.h>
#include <stdint.h>

// MAHA decoder block, MI355X/gfx950.
// B=2, N=2048, D=1024, H=16(dh=64), L=3, R=2, HID=2734(->2816 pad), fp32 I/O.
// Needs ~175 MB of d_ws.

#define B_   2
#define N_   2048
#define D_   1024
#define H_   16
#define DH_  64
#define HID_ 2734
#define HIDP 2816
#define CNT  (B_*N_*D_)   // 4194304

typedef unsigned short u16;
typedef __attribute__((ext_vector_type(8))) short short8;
typedef __attribute__((ext_vector_type(4))) float f32x4;

__device__ __forceinline__ u16 f2bf(float f) {
  uint32_t u = __builtin_bit_cast(uint32_t, f);
  u += 0x7fffu + ((u >> 16) & 1u);          // RNE
  return (u16)(u >> 16);
}
__device__ __forceinline__ float bf2f(u16 h) {
  uint32_t u = ((uint32_t)h) << 16;
  return __builtin_bit_cast(float, u);
}
__device__ __forceinline__ void gload_lds16(const void* g, void* l) {
  __builtin_amdgcn_global_load_lds(
      (const __attribute__((address_space(1))) uint32_t*)g,
      (__attribute__((address_space(3))) uint32_t*)l, 16, 0, 0);
}

// ---------------- fp32 [K,N] -> bf16 BT [NP,KP] transpose+convert (+scale, zero-pad) ----
__global__ __launch_bounds__(256) void twconv_k(const float* __restrict__ W, u16* __restrict__ BT,
                                                int K, int N, int KP, int NP, float scale) {
  __shared__ float t[32][33];
  const int tx = threadIdx.x & 31, ty = threadIdx.x >> 5;   // 32 x 8
  const int nb = blockIdx.x * 32, kb = blockIdx.y * 32;
  #pragma unroll
  for (int i = 0; i < 4; i++) {
    int k = kb + ty + i*8, n = nb + tx;
    t[ty + i*8][tx] = (k < K && n < N) ? W[(size_t)k * N + n] * scale : 0.f;
  }
  __syncthreads();
  #pragma unroll
  for (int i = 0; i < 4; i++) {
    int n = nb + ty + i*8, k = kb + tx;
    if (n < NP && k < KP) BT[(size_t)n * KP + k] = f2bf(t[tx][ty + i*8]);
  }
}

// ---------------- RMSNorm: fp32 row [rows, D] -> bf16 ----------------
__global__ __launch_bounds__(256) void rmsnorm_k(const float* __restrict__ x,
                                                 const float* __restrict__ w,
                                                 u16* __restrict__ out) {
  const int row = blockIdx.x;
  const float* xr = x + (size_t)row * D_;
  float ss = 0.f;
  #pragma unroll
  for (int i = 0; i < 4; i++) { float v = xr[threadIdx.x + i*256]; ss += v*v; }
  ss += __shfl_xor(ss, 1);  ss += __shfl_xor(ss, 2);  ss += __shfl_xor(ss, 4);
  ss += __shfl_xor(ss, 8);  ss += __shfl_xor(ss, 16); ss += __shfl_xor(ss, 32);
  __shared__ float red[4];
  if ((threadIdx.x & 63) == 0) red[threadIdx.x >> 6] = ss;
  __syncthreads();
  float sc = rsqrtf((red[0]+red[1]+red[2]+red[3]) * (1.f/D_) + 1e-6f);
  #pragma unroll
  for (int i = 0; i < 4; i++) {
    int c = threadIdx.x + i*256;
    out[(size_t)row * D_ + c] = f2bf(xr[c] * w[c] * sc);
  }
}

// ---------------- avg-pool by 2 along seq (bf16) ----------------
__global__ __launch_bounds__(256) void pool_k(const u16* __restrict__ in, u16* __restrict__ out, int No) {
  const int total = B_ * No * D_;
  const int nod = No << 10;
  for (int i = blockIdx.x*256 + threadIdx.x; i < total; i += gridDim.x*256) {
    int b = i / nod; int rem = i - b*nod; int j = rem >> 10; int d = rem & 1023;
    size_t src = ((size_t)(b*2*No + 2*j)) * D_ + d;
    out[i] = f2bf(0.5f * (bf2f(in[src]) + bf2f(in[src + D_])));
  }
}

// ---------------- 128x128 bf16 MFMA GEMM, C = A[M,K] * BT[N,K]^T ----------------
__global__ __launch_bounds__(256) void gemm_bt(const u16* __restrict__ A, const u16* __restrict__ BT,
                                               void* __restrict__ Cv, int M, int N, int K, int c_bf16) {
  __shared__ __align__(16) u16 As[128*32];
  __shared__ __align__(16) u16 Bs[128*32];
  const int tid = threadIdx.x;
  const int lane = tid & 63, wid = tid >> 6;
  const int quad = lane >> 4, c16 = lane & 15;
  const int m0 = blockIdx.y * 128, n0 = blockIdx.x * 128;
  const int wm = wid >> 1, wn = wid & 1;

  f32x4 acc[4][4];
  #pragma unroll
  for (int i = 0; i < 4; i++)
    #pragma unroll
    for (int j = 0; j < 4; j++) acc[i][j] = f32x4{0.f,0.f,0.f,0.f};

  const int srow = lane >> 2, sch = (lane & 3) * 8;
  for (int k0 = 0; k0 < K; k0 += 32) {
    #pragma unroll
    for (int t = 0; t < 2; t++) {
      int idx = wid*2 + t;            // 0..7, each stages 16 rows (1 KB)
      int row = idx*16 + srow;
      gload_lds16(A  + (size_t)(m0+row)*K + k0 + sch, As + idx*512);
      gload_lds16(BT + (size_t)(n0+row)*K + k0 + sch, Bs + idx*512);
    }
    __syncthreads();
    short8 af[4], bfr[4];
    #pragma unroll
    for (int mt = 0; mt < 4; mt++) af[mt]  = *(const short8*)(As + (wm*64 + mt*16 + c16)*32 + quad*8);
    #pragma unroll
    for (int nt = 0; nt < 4; nt++) bfr[nt] = *(const short8*)(Bs + (wn*64 + nt*16 + c16)*32 + quad*8);
    #pragma unroll
    for (int mt = 0; mt < 4; mt++)
      #pragma unroll
      for (int nt = 0; nt < 4; nt++)
        acc[mt][nt] = __builtin_amdgcn_mfma_f32_16x16x32_bf16(af[mt], bfr[nt], acc[mt][nt], 0, 0, 0);
    __syncthreads();
  }
  if (c_bf16) {
    u16* C = (u16*)Cv;
    #pragma unroll
    for (int mt = 0; mt < 4; mt++)
      #pragma unroll
      for (int nt = 0; nt < 4; nt++)
        #pragma unroll
        for (int r = 0; r < 4; r++) {
          int row = m0 + wm*64 + mt*16 + quad*4 + r;
          int col = n0 + wn*64 + nt*16 + c16;
          C[(size_t)row * N + col] = f2bf(acc[mt][nt][r]);
        }
  } else {
    float* C = (float*)Cv;
    #pragma unroll
    for (int mt = 0; mt < 4; mt++)
      #pragma unroll
      for (int nt = 0; nt < 4; nt++)
        #pragma unroll
        for (int r = 0; r < 4; r++) {
          int row = m0 + wm*64 + mt*16 + quad*4 + r;
          int col = n0 + wn*64 + nt*16 + c16;
          C[(size_t)row * N + col] = acc[mt][nt][r];
        }
  }
}

// ---------------- MFMA flash attention (causal, dh=64, bf16 QKV, scale folded in Wq) ----
// grid: (Nl/64, B*H); block 256 = 4 waves; wave w handles queries [qt*64+w*16, +16)
__global__ __launch_bounds__(256) void flash_k(const u16* __restrict__ Qg, const u16* __restrict__ Kg,
                                               const u16* __restrict__ Vg, u16* __restrict__ Og, int Nl) {
  __shared__ __align__(16) u16 Kt[2*64*32];   // [dh-panel][key][32]
  __shared__ __align__(16) u16 Vt[2*64*32];   // [key-panel][dh][32]
  __shared__ __align__(16) u16 Pl[4*16*88];   // per-wave P, padded rows (88)
  const int tid = threadIdx.x;
  const int lane = tid & 63, wid = tid >> 6;
  const int quad = lane >> 4, c16 = lane & 15;
  const int qt = blockIdx.x;
  const int b = blockIdx.y >> 4, h = blockIdx.y & 15;
  const size_t base = (size_t)b * Nl * D_ + h * DH_;

  short8 aq0, aq1;
  {
    const u16* qp = Qg + base + (size_t)(qt*64 + wid*16 + c16) * D_ + quad*8;
    aq0 = *(const short8*)qp;
    aq1 = *(const short8*)(qp + 32);
  }
  f32x4 oacc[4];
  #pragma unroll
  for (int nt = 0; nt < 4; nt++) oacc[nt] = f32x4{0.f,0.f,0.f,0.f};
  float mrow[4] = {-1e30f,-1e30f,-1e30f,-1e30f};
  float lrow[4] = {0.f,0.f,0.f,0.f};
  u16* Pw = Pl + wid * (16*88);

  for (int kt = 0; kt <= qt; kt++) {
    const int k0 = kt * 64;
    __syncthreads();
    // stage K: [key][dh] -> two [64][32] panels, async direct-to-LDS
    #pragma unroll
    for (int t = 0; t < 2; t++) {
      int idx = wid*2 + t;
      int p = idx >> 2;
      int key = (idx & 3)*16 + (lane >> 2);
      gload_lds16(Kg + base + (size_t)(k0+key)*D_ + p*32 + (lane & 3)*8, Kt + idx*512);
    }
    // stage V transposed: Vt[key-panel][dh][key%32]
    #pragma unroll
    for (int c2 = 0; c2 < 2; c2++) {
      int ch = wid + 4*c2;                     // dh chunk of 8
      short8 v8 = *(const short8*)(Vg + base + (size_t)(k0+lane)*D_ + ch*8);
      int sp = lane >> 5, kl = lane & 31;
      #pragma unroll
      for (int j = 0; j < 8; j++)
        Vt[sp*2048 + (ch*8 + j)*32 + kl] = (u16)v8[j];
    }
    __syncthreads();

    // S = Q K^T   (C-layout: row=q=quad*4+r, col=key=c16+nt*16)
    f32x4 s4[4];
    #pragma unroll
    for (int nt = 0; nt < 4; nt++) {
      f32x4 a = f32x4{0.f,0.f,0.f,0.f};
      short8 b0 = *(const short8*)(Kt +        (nt*16 + c16)*32 + quad*8);
      short8 b1 = *(const short8*)(Kt + 2048 + (nt*16 + c16)*32 + quad*8);
      a = __builtin_amdgcn_mfma_f32_16x16x32_bf16(aq0, b0, a, 0, 0, 0);
      a = __builtin_amdgcn_mfma_f32_16x16x32_bf16(aq1, b1, a, 0, 0, 0);
      s4[nt] = a;
    }
    if (kt == qt) {
      #pragma unroll
      for (int nt = 0; nt < 4; nt++)
        #pragma unroll
        for (int r = 0; r < 4; r++) {
          int qrow = qt*64 + wid*16 + quad*4 + r;
          int key  = k0 + nt*16 + c16;
          if (key > qrow) s4[nt][r] = -1e9f;
        }
    }
    // online softmax per row (16-lane groups share a row set)
    float al[4];
    #pragma unroll
    for (int r = 0; r < 4; r++) {
      float v = fmaxf(fmaxf(s4[0][r], s4[1][r]), fmaxf(s4[2][r], s4[3][r]));
      v = fmaxf(v, __shfl_xor(v, 1)); v = fmaxf(v, __shfl_xor(v, 2));
      v = fmaxf(v, __shfl_xor(v, 4)); v = fmaxf(v, __shfl_xor(v, 8));
      float mn = fmaxf(mrow[r], v);
      al[r] = __expf(mrow[r] - mn);
      mrow[r] = mn;
      #pragma unroll
      for (int nt = 0; nt < 4; nt++) s4[nt][r] = __expf(s4[nt][r] - mn);
      float sum = s4[0][r] + s4[1][r] + s4[2][r] + s4[3][r];
      sum += __shfl_xor(sum, 1); sum += __shfl_xor(sum, 2);
      sum += __shfl_xor(sum, 4); sum += __shfl_xor(sum, 8);
      lrow[r] = lrow[r]*al[r] + sum;
    }
    // rescale O, write P (bf16) to per-wave LDS in C-layout
    #pragma unroll
    for (int nt = 0; nt < 4; nt++)
      #pragma unroll
      for (int r = 0; r < 4; r++) {
        oacc[nt][r] *= al[r];
        Pw[(quad*4 + r)*88 + nt*16 + c16] = f2bf(s4[nt][r]);
      }
    // re-read P as A-operand frags; O += P V
    short8 ap0 = *(const short8*)(Pw + c16*88 +      quad*8);
    short8 ap1 = *(const short8*)(Pw + c16*88 + 32 + quad*8);
    #pragma unroll
    for (int nt = 0; nt < 4; nt++) {
      short8 bv0 = *(const short8*)(Vt +        (nt*16 + c16)*32 + quad*8);
      short8 bv1 = *(const short8*)(Vt + 2048 + (nt*16 + c16)*32 + quad*8);
      oacc[nt] = __builtin_amdgcn_mfma_f32_16x16x32_bf16(ap0, bv0, oacc[nt], 0, 0, 0);
      oacc[nt] = __builtin_amdgcn_mfma_f32_16x16x32_bf16(ap1, bv1, oacc[nt], 0, 0, 0);
    }
  }
  #pragma unroll
  for (int nt = 0; nt < 4; nt++)
    #pragma unroll
    for (int r = 0; r < 4; r++) {
      int qrow = qt*64 + wid*16 + quad*4 + r;
      Og[base + (size_t)qrow*D_ + nt*16 + c16] = f2bf(oacc[nt][r] / lrow[r]);
    }
}

// ---------------- Gram matrix of the 3 (coarse) Y tensors over the repeat map ----------
__global__ __launch_bounds__(256) void gram_k(const float* __restrict__ Y0, const float* __restrict__ Y1,
                                              const float* __restrict__ Y2, float* __restrict__ G) {
  float a[6] = {0,0,0,0,0,0};
  for (int i = blockIdx.x*256 + threadIdx.x; i < CNT; i += gridDim.x*256) {
    int d = i & 1023; int n = (i >> 10) & (N_-1); int b = i >> 21;
    float y0 = Y0[i];
    float y1 = Y1[(((size_t)b*(N_/2) + (n>>1)) << 10) + d];
    float y2 = Y2[(((size_t)b*(N_/4) + (n>>2)) << 10) + d];
    a[0] += y0*y0; a[1] += y0*y1; a[2] += y0*y2;
    a[3] += y1*y1; a[4] += y1*y2; a[5] += y2*y2;
  }
  __shared__ float red[4][6];
  const int lane = threadIdx.x & 63, wid = threadIdx.x >> 6;
  #pragma unroll
  for (int t = 0; t < 6; t++) {
    float v = a[t];
    v += __shfl_xor(v, 1);  v += __shfl_xor(v, 2);  v += __shfl_xor(v, 4);
    v += __shfl_xor(v, 8);  v += __shfl_xor(v, 16); v += __shfl_xor(v, 32);
    a[t] = v;
  }
  if (lane == 0)
    #pragma unroll
    for (int t = 0; t < 6; t++) red[wid][t] = a[t];
  __syncthreads();
  if (threadIdx.x < 6)
    atomicAdd(&G[threadIdx.x], red[0][threadIdx.x] + red[1][threadIdx.x] +
                               red[2][threadIdx.x] + red[3][threadIdx.x]);
}

__global__ void zero_k(float* p) { if (threadIdx.x < 64) p[threadIdx.x] = 0.f; }

// ---------------- Nash iterations + aux loss + both Sinkhorns (scalar) ----------------
__global__ void head_k(float* SC, const float* __restrict__ agg, const float* __restrict__ mA,
                       const float* __restrict__ mF, float* __restrict__ aux_out) {
  if (threadIdx.x != 0 || blockIdx.x != 0) return;
  float G[6];
  for (int t = 0; t < 6; t++) G[t] = SC[t];
  const int gi[3][3] = {{0,1,2},{1,3,4},{2,4,5}};
  float a[3] = {agg[0], agg[1], agg[2]};
  float w[3];
  {
    float m = fmaxf(a[0], fmaxf(a[1], a[2])); float s = 0.f;
    for (int l = 0; l < 3; l++) { w[l] = expf(a[l]-m); s += w[l]; }
    for (int l = 0; l < 3; l++) w[l] /= s;
  }
  const float inv = 1.f / (float)CNT;
  for (int it = 0; it < 3; it++) {
    float q = 0.f;
    for (int l = 0; l < 3; l++) for (int m2 = 0; m2 < 3; m2++) q += w[l]*w[m2]*G[gi[l][m2]];
    float z[3];
    for (int l = 0; l < 3; l++) {
      float dot = w[0]*G[gi[l][0]] + w[1]*G[gi[l][1]] + w[2]*G[gi[l][2]];
      z[l] = a[l] - (G[gi[l][l]] - 2.f*dot + q) * inv;
    }
    float m = fmaxf(z[0], fmaxf(z[1], z[2])); float s = 0.f;
    for (int l = 0; l < 3; l++) { w[l] = expf(z[l]-m); s += w[l]; }
    for (int l = 0; l < 3; l++) w[l] /= s;
  }
  SC[6] = w[0]; SC[7] = w[1]; SC[8] = w[2];
  aux_out[0] = w[0]*logf(w[0]*3.f + 1e-9f) + w[1]*logf(w[1]*3.f + 1e-9f) + w[2]*logf(w[2]*3.f + 1e-9f);
  // sinkhorn(mhc_attn) -> SC[9],SC[10]; sinkhorn(mhc_ffn) -> SC[11],SC[12]
  for (int which = 0; which < 2; which++) {
    const float* Lg = which ? mF : mA;
    float M0 = expf(Lg[0]), M1 = expf(Lg[1]), M2 = expf(Lg[2]), M3 = expf(Lg[3]);
    for (int i2 = 0; i2 < 10; i2++) {
      float r0 = M0+M1, r1 = M2+M3; M0 /= r0; M1 /= r0; M2 /= r1; M3 /= r1;
      float c0 = M0+M2, c1 = M1+M3; M0 /= c0; M2 /= c0; M1 /= c1; M3 /= c1;
    }
    SC[9 + which*2] = M0; SC[10 + which*2] = M1;
  }
}

// ---------------- x1 = P00*x + P01*sum_l w_l * Y_l(upsampled) ----------------
__global__ __launch_bounds__(256) void mix1_k(const float* __restrict__ x, const float* __restrict__ Y0,
                                              const float* __restrict__ Y1, const float* __restrict__ Y2,
                                              const float* __restrict__ SC, float* __restrict__ x1) {
  const float w0 = SC[6], w1 = SC[7], w2 = SC[8], p0 = SC[9], p1 = SC[10];
  for (int i = blockIdx.x*256 + threadIdx.x; i < CNT; i += gridDim.x*256) {
    int d = i & 1023; int n = (i >> 10) & (N_-1); int b = i >> 21;
    float y = w0 * Y0[i]
            + w1 * Y1[(((size_t)b*(N_/2) + (n>>1)) << 10) + d]
            + w2 * Y2[(((size_t)b*(N_/4) + (n>>2)) << 10) + d];
    x1[i] = p0 * x[i] + p1 * y;
  }
}

__global__ __launch_bounds__(256) void silumul_k(const u16* __restrict__ g, const u16* __restrict__ u,
                                                 u16* __restrict__ h, int total) {
  for (int i = blockIdx.x*256 + threadIdx.x; i < total; i += gridDim.x*256) {
    float gv = bf2f(g[i]), uv = bf2f(u[i]);
    h[i] = f2bf(gv / (1.f + __expf(-gv)) * uv);
  }
}

__global__ __launch_bounds__(256) void final_k(const float* __restrict__ x1, const float* __restrict__ ffn,
                                               const float* __restrict__ SC, float* __restrict__ out) {
  const float q0 = SC[11], q1 = SC[12];
  for (int i = blockIdx.x*256 + threadIdx.x; i < CNT; i += gridDim.x*256)
    out[i] = q0 * x1[i] + q1 * ffn[i];
}

// ================================ host launcher ================================
extern "C" void kernel_launch(void* const* d_in, const int* in_sizes, int n_in,
                              void* d_out, int out_size, void* d_ws, size_t ws_size,
                              hipStream_t stream) {
  (void)in_sizes; (void)n_in; (void)out_size; (void)ws_size;
  const float* x    = (const float*)d_in[0];
  const float* nw1  = (const float*)d_in[1];
  const float* nw2  = (const float*)d_in[2];
  const float* Wdec = (const float*)d_in[3];
  const float* Wq   = (const float*)d_in[4];
  const float* Wk   = (const float*)d_in[5];
  const float* Wv   = (const float*)d_in[6];
  const float* Wo   = (const float*)d_in[7];
  const float* agg  = (const float*)d_in[8];
  const float* Wg   = (const float*)d_in[9];
  const float* Wu   = (const float*)d_in[10];
  const float* Wdn  = (const float*)d_in[11];
  const float* mA   = (const float*)d_in[12];
  const float* mF   = (const float*)d_in[13];
  float* out = (float*)d_out;

  char* ws = (char*)d_ws;
  size_t off = 0;
  auto take = [&](size_t b) { size_t r = off; off += (b + 255) & ~(size_t)255; return r; };

  u16 *WdecT[3], *WqT[3], *WkT[3];
  for (int l = 0; l < 3; l++) WdecT[l] = (u16*)(ws + take(2097152));
  for (int l = 0; l < 3; l++) WqT[l]   = (u16*)(ws + take(2097152));
  for (int l = 0; l < 3; l++) WkT[l]   = (u16*)(ws + take(2097152));
  u16* WvT  = (u16*)(ws + take(2097152));
  u16* WoT  = (u16*)(ws + take(2097152));
  u16* WgT  = (u16*)(ws + take((size_t)HIDP*1024*2));
  u16* WuT  = (u16*)(ws + take((size_t)HIDP*1024*2));
  u16* WdnT = (u16*)(ws + take((size_t)1024*HIDP*2));
  u16* xn_bf  = (u16*)(ws + take(8388608));   // reused as xn2 in FFN phase
  u16* xp1_bf = (u16*)(ws + take(4194304));
  u16* xp2_bf = (u16*)(ws + take(2097152));
  const size_t bigbase = off;                 // S/Q/K/V/O region, aliased by FFN buffers
  const size_t szl[3] = {8388608, 4194304, 2097152};
  u16 *Sb[3], *Qb[3], *Kb[3], *Vb[3], *Ob[3];
  for (int l = 0; l < 3; l++) Sb[l] = (u16*)(ws + take(szl[l]));
  for (int l = 0; l < 3; l++) Qb[l] = (u16*)(ws + take(szl[l]));
  for (int l = 0; l < 3; l++) Kb[l] = (u16*)(ws + take(szl[l]));
  for (int l = 0; l < 3; l++) Vb[l] = (u16*)(ws + take(szl[l]));
  for (int l = 0; l < 3; l++) Ob[l] = (u16*)(ws + take(szl[l]));
  float* YC[3];
  YC[0] = (float*)(ws + take(16777216));
  YC[1] = (float*)(ws + take(8388608));
  YC[2] = (float*)(ws + take(4194304));
  float* x1  = (float*)(ws + take(16777216));
  float* SCb = (float*)(ws + take(256));
  // FFN aliases over the (then-dead) S/Q/K/V/O region
  u16*   g_bf = (u16*)(ws + bigbase);
  u16*   u_bf = (u16*)(ws + bigbase + 23068672);
  float* ffn  = (float*)(ws + bigbase + 46137344);

  dim3 blk(256);
  // ---- weights: fp32 -> bf16, transposed to [N,K], zero-padded; 1/8 folded into Wq ----
  for (int l = 0; l < 3; l++)
    twconv_k<<<dim3(32,32), blk, 0, stream>>>(Wdec + (size_t)l*1048576, WdecT[l], 1024,1024,1024,1024, 1.f);
  for (int l = 0; l < 3; l++)
    twconv_k<<<dim3(32,32), blk, 0, stream>>>(Wq + (size_t)l*1048576, WqT[l], 1024,1024,1024,1024, 0.125f);
  for (int l = 0; l < 3; l++)
    twconv_k<<<dim3(32,32), blk, 0, stream>>>(Wk + (size_t)l*1048576, WkT[l], 1024,1024,1024,1024, 1.f);
  twconv_k<<<dim3(32,32), blk, 0, stream>>>(Wv, WvT, 1024,1024,1024,1024, 1.f);
  twconv_k<<<dim3(32,32), blk, 0, stream>>>(Wo, WoT, 1024,1024,1024,1024, 1.f);
  twconv_k<<<dim3(88,32), blk, 0, stream>>>(Wg,  WgT,  1024, HID_, 1024, HIDP, 1.f);
  twconv_k<<<dim3(88,32), blk, 0, stream>>>(Wu,  WuT,  1024, HID_, 1024, HIDP, 1.f);
  twconv_k<<<dim3(32,88), blk, 0, stream>>>(Wdn, WdnT, HID_, 1024, HIDP, 1024, 1.f);

  // ---- attention branch ----
  rmsnorm_k<<<4096, blk, 0, stream>>>(x, nw1, xn_bf);
  pool_k<<<1024, blk, 0, stream>>>(xn_bf,  xp1_bf, 1024);
  pool_k<<<512,  blk, 0, stream>>>(xp1_bf, xp2_bf, 512);

  const int Ms[3] = {4096, 2048, 1024};     // B * N_l rows
  const int Ns[3] = {2048, 1024, 512};      // N_l
  u16* XNl[3] = {xn_bf, xp1_bf, xp2_bf};
  for (int l = 0; l < 3; l++)
    gemm_bt<<<dim3(8, Ms[l]/128), blk, 0, stream>>>(XNl[l], WdecT[l], Sb[l], Ms[l], 1024, 1024, 1);
  for (int l = 0; l < 3; l++) {
    gemm_bt<<<dim3(8, Ms[l]/128), blk, 0, stream>>>(Sb[l], WqT[l], Qb[l], Ms[l], 1024, 1024, 1);
    gemm_bt<<<dim3(8, Ms[l]/128), blk, 0, stream>>>(Sb[l], WkT[l], Kb[l], Ms[l], 1024, 1024, 1);
    gemm_bt<<<dim3(8, Ms[l]/128), blk, 0, stream>>>(Sb[l], WvT,    Vb[l], Ms[l], 1024, 1024, 1);
  }
  for (int l = 0; l < 3; l++)
    flash_k<<<dim3(Ns[l]/64, B_*H_), blk, 0, stream>>>(Qb[l], Kb[l], Vb[l], Ob[l], Ns[l]);
  for (int l = 0; l < 3; l++)
    gemm_bt<<<dim3(8, Ms[l]/128), blk, 0, stream>>>(Ob[l], WoT, YC[l], Ms[l], 1024, 1024, 0);

  zero_k<<<1, 64, 0, stream>>>(SCb);
  gram_k<<<1024, blk, 0, stream>>>(YC[0], YC[1], YC[2], SCb);
  head_k<<<1, 64, 0, stream>>>(SCb, agg, mA, mF, out + CNT);
  mix1_k<<<2048, blk, 0, stream>>>(x, YC[0], YC[1], YC[2], SCb, x1);

  // ---- FFN branch ----
  rmsnorm_k<<<4096, blk, 0, stream>>>(x1, nw2, xn_bf);
  gemm_bt<<<dim3(HIDP/128, 32), blk, 0, stream>>>(xn_bf, WgT, g_bf, 4096, HIDP, 1024, 1);
  gemm_bt<<<dim3(HIDP/128, 32), blk, 0, stream>>>(xn_bf, WuT, u_bf, 4096, HIDP, 1024, 1);
  silumul_k<<<2048, blk, 0, stream>>>(g_bf, u_bf, g_bf, 4096*HIDP);
  gemm_bt<<<dim3(8, 32), blk, 0, stream>>>(g_bf, WdnT, ffn, 4096, 1024, HIDP, 0);
  final_k<<<2048, blk, 0, stream>>>(x1, ffn, SCb, out);
}

// Round 2
// 685.088 us; speedup vs baseline: 1.4413x; 1.4413x over previous
//
#include <hip/hip_runtime.h>
#include <stdint.h>

// MAHA decoder block, MI355X/gfx950. Round 2.
// B=2, N=2048, D=1024, H=16(dh=64), L=3, R=2, HID=2734(->2816), fp32 I/O.
// ~196 MB of d_ws.

#define B_   2
#define N_   2048
#define D_   1024
#define H_   16
#define DH_  64
#define HID_ 2734
#define HIDP 2816
#define CNT  (B_*N_*D_)   // 4194304
#define LOG2E 1.4426950408889634f

typedef unsigned short u16;
typedef __attribute__((ext_vector_type(8))) short short8;
typedef __attribute__((ext_vector_type(4))) float f32x4;
typedef __attribute__((ext_vector_type(4))) uint16_t u16x4;

__device__ __forceinline__ u16 f2bf(float f) {
  uint32_t u = __builtin_bit_cast(uint32_t, f);
  u += 0x7fffu + ((u >> 16) & 1u);          // RNE
  return (u16)(u >> 16);
}
__device__ __forceinline__ float bf2f(u16 h) {
  uint32_t u = ((uint32_t)h) << 16;
  return __builtin_bit_cast(float, u);
}
__device__ __forceinline__ void gload_lds16(const void* g, void* l) {
  __builtin_amdgcn_global_load_lds(
      (const __attribute__((address_space(1))) uint32_t*)g,
      (__attribute__((address_space(3))) uint32_t*)l, 16, 0, 0);
}

// ---------------- fp32 [K,N] -> bf16 BT [NP,KP] transpose+convert (+scale, zero-pad) ----
__global__ __launch_bounds__(256) void twconv_k(const float* __restrict__ W, u16* __restrict__ BT,
                                                int K, int N, int KP, int NP, float scale) {
  __shared__ float t[32][33];
  const int tx = threadIdx.x & 31, ty = threadIdx.x >> 5;   // 32 x 8
  const int nb = blockIdx.x * 32, kb = blockIdx.y * 32;
  #pragma unroll
  for (int i = 0; i < 4; i++) {
    int k = kb + ty + i*8, n = nb + tx;
    t[ty + i*8][tx] = (k < K && n < N) ? W[(size_t)k * N + n] * scale : 0.f;
  }
  __syncthreads();
  #pragma unroll
  for (int i = 0; i < 4; i++) {
    int n = nb + ty + i*8, k = kb + tx;
    if (n < NP && k < KP) BT[(size_t)n * KP + k] = f2bf(t[tx][ty + i*8]);
  }
}

// ---------------- plain fp32 -> bf16 convert ----------------
__global__ __launch_bounds__(256) void conv_k(const float* __restrict__ in, u16* __restrict__ out, int total) {
  for (int i = blockIdx.x*256 + threadIdx.x; i < total; i += gridDim.x*256)
    out[i] = f2bf(in[i]);
}

// ---------------- RMSNorm: fp32 row [rows, D] -> bf16 ----------------
__global__ __launch_bounds__(256) void rmsnorm_k(const float* __restrict__ x,
                                                 const float* __restrict__ w,
                                                 u16* __restrict__ out) {
  const int row = blockIdx.x;
  const float* xr = x + (size_t)row * D_;
  float ss = 0.f;
  #pragma unroll
  for (int i = 0; i < 4; i++) { float v = xr[threadIdx.x + i*256]; ss += v*v; }
  ss += __shfl_xor(ss, 1);  ss += __shfl_xor(ss, 2);  ss += __shfl_xor(ss, 4);
  ss += __shfl_xor(ss, 8);  ss += __shfl_xor(ss, 16); ss += __shfl_xor(ss, 32);
  __shared__ float red[4];
  if ((threadIdx.x & 63) == 0) red[threadIdx.x >> 6] = ss;
  __syncthreads();
  float sc = rsqrtf((red[0]+red[1]+red[2]+red[3]) * (1.f/D_) + 1e-6f);
  #pragma unroll
  for (int i = 0; i < 4; i++) {
    int c = threadIdx.x + i*256;
    out[(size_t)row * D_ + c] = f2bf(xr[c] * w[c] * sc);
  }
}

// ---------------- avg-pool by 2 along seq (bf16) ----------------
__global__ __launch_bounds__(256) void pool_k(const u16* __restrict__ in, u16* __restrict__ out, int No) {
  const int total = B_ * No * D_;
  const int nod = No << 10;
  for (int i = blockIdx.x*256 + threadIdx.x; i < total; i += gridDim.x*256) {
    int b = i / nod; int rem = i - b*nod; int j = rem >> 10; int d = rem & 1023;
    size_t src = ((size_t)(b*2*No + 2*j)) * D_ + d;
    out[i] = f2bf(0.5f * (bf2f(in[src]) + bf2f(in[src + D_])));
  }
}

// ---------------- 128x128 bf16 MFMA GEMM, C = A[M,K] * BT[N,K]^T ----------------
// Optional per-row-range BT selection: level = (y>=t2)?2:(y>=t1)?1:0; BT += level*bt_stride.
__global__ __launch_bounds__(256) void gemm_bt(const u16* __restrict__ A, const u16* __restrict__ BT,
                                               void* __restrict__ Cv, int N, int K, int c_bf16,
                                               int t1, int t2, unsigned int bt_stride) {
  __shared__ __align__(16) u16 As[128*32];
  __shared__ __align__(16) u16 Bs[128*32];
  const int tid = threadIdx.x;
  const int lane = tid & 63, wid = tid >> 6;
  const int quad = lane >> 4, c16 = lane & 15;
  const int y = blockIdx.y;
  const int m0 = y * 128, n0 = blockIdx.x * 128;
  const int wm = wid >> 1, wn = wid & 1;
  const int level = (y >= t2) ? 2 : ((y >= t1) ? 1 : 0);
  BT += (size_t)level * bt_stride;

  f32x4 acc[4][4];
  #pragma unroll
  for (int i = 0; i < 4; i++)
    #pragma unroll
    for (int j = 0; j < 4; j++) acc[i][j] = f32x4{0.f,0.f,0.f,0.f};

  const int srow = lane >> 2;             // row within 16-row stage group
  const int schunk = lane & 3;            // 16B slot chunk
  for (int k0 = 0; k0 < K; k0 += 32) {
    #pragma unroll
    for (int t = 0; t < 2; t++) {
      int idx = wid*2 + t;                // 0..7, each stages 16 rows (1 KB)
      int row = idx*16 + srow;
      int g = (schunk ^ ((row >> 1) & 3)) * 8;    // xor-swizzled global chunk
      gload_lds16(A  + (size_t)(m0+row)*K + k0 + g, As + idx*512);
      gload_lds16(BT + (size_t)(n0+row)*K + k0 + g, Bs + idx*512);
    }
    __syncthreads();
    short8 af[4], bfr[4];
    #pragma unroll
    for (int mt = 0; mt < 4; mt++) {
      int ar = wm*64 + mt*16 + c16;
      af[mt]  = *(const short8*)(As + ar*32 + (quad ^ ((ar>>1)&3))*8);
    }
    #pragma unroll
    for (int nt = 0; nt < 4; nt++) {
      int br = wn*64 + nt*16 + c16;
      bfr[nt] = *(const short8*)(Bs + br*32 + (quad ^ ((br>>1)&3))*8);
    }
    #pragma unroll
    for (int mt = 0; mt < 4; mt++)
      #pragma unroll
      for (int nt = 0; nt < 4; nt++)
        acc[mt][nt] = __builtin_amdgcn_mfma_f32_16x16x32_bf16(af[mt], bfr[nt], acc[mt][nt], 0, 0, 0);
    __syncthreads();
  }
  if (c_bf16) {
    u16* C = (u16*)Cv;
    #pragma unroll
    for (int mt = 0; mt < 4; mt++)
      #pragma unroll
      for (int nt = 0; nt < 4; nt++)
        #pragma unroll
        for (int r = 0; r < 4; r++) {
          int row = m0 + wm*64 + mt*16 + quad*4 + r;
          int col = n0 + wn*64 + nt*16 + c16;
          C[(size_t)row * N + col] = f2bf(acc[mt][nt][r]);
        }
  } else {
    float* C = (float*)Cv;
    #pragma unroll
    for (int mt = 0; mt < 4; mt++)
      #pragma unroll
      for (int nt = 0; nt < 4; nt++)
        #pragma unroll
        for (int r = 0; r < 4; r++) {
          int row = m0 + wm*64 + mt*16 + quad*4 + r;
          int col = n0 + wn*64 + nt*16 + c16;
          C[(size_t)row * N + col] = acc[mt][nt][r];
        }
  }
}

// ---------------- bf16 transpose: V part of QKV -> VT [b][c][n] ----------------
// grid (Nl/32, 32, B); in = QKV + rowbase*3072 + 2048
__global__ __launch_bounds__(256) void vtrans_k(const u16* __restrict__ in, u16* __restrict__ out, int Nl) {
  __shared__ u16 t[32][33];
  const int n0 = blockIdx.x*32, c0 = blockIdx.y*32, b = blockIdx.z;
  const int tx = threadIdx.x & 31, ty = threadIdx.x >> 5;
  #pragma unroll
  for (int i = 0; i < 4; i++)
    t[ty + i*8][tx] = in[(size_t)(b*Nl + n0 + ty + i*8)*3072 + c0 + tx];
  __syncthreads();
  #pragma unroll
  for (int i = 0; i < 4; i++)
    out[(size_t)(b*1024 + c0 + ty + i*8)*Nl + n0 + tx] = t[tx][ty + i*8];
}

// ---------------- MFMA flash attention (causal, dh=64), transposed-S formulation ----
// grid: (Nl/64, B*H); block 256 = 4 waves; wave w handles queries [qt*64+w*16, +16)
// QKVg: rows [b*Nl+n][3072] (Q at col h*64, K at 1024+h*64); VTg: [b][c][Nl]; Og rows [b*Nl+n][1024]
__global__ __launch_bounds__(256) void flash_k(const u16* __restrict__ QKVg,
                                               const u16* __restrict__ VTg,
                                               u16* __restrict__ Og, int Nl) {
  __shared__ __align__(16) u16 Kt[2][64*64];   // [key][dh], xor chunk swizzle
  __shared__ __align__(16) u16 Vt[2][64*64];   // [dh][key], xor chunk swizzle
  __shared__ __align__(16) u16 Ps[4][16*68];   // per-wave P [q][key], stride 68
  const int tid = threadIdx.x, lane = tid & 63, wid = tid >> 6;
  const int quad = lane >> 4, c16 = lane & 15;
  const int qt = gridDim.x - 1 - blockIdx.x;   // long blocks first
  const int b = blockIdx.y >> 4, h = blockIdx.y & 15;
  const size_t qkbase = (size_t)b * Nl * 3072 + h * 64;
  const size_t vbase  = ((size_t)(b*16 + h) * 64) * (size_t)Nl;
  const int qrow = qt*64 + wid*16 + c16;

  // Q as B-operand: n=q=c16, k(dh)=quad*8+j
  short8 bq0, bq1;
  {
    const u16* qp = QKVg + qkbase + (size_t)qrow*3072 + quad*8;
    bq0 = *(const short8*)qp;
    bq1 = *(const short8*)(qp + 32);
  }
  // staging source per-lane constants (2 DMA insts per wave per tensor)
  const int si0 = wid*2, si1 = wid*2 + 1;
  const int sr0 = si0*8 + (lane>>3), sr1 = si1*8 + (lane>>3);  // key (K) / dh (V)
  const int sg  = ((lane&7) ^ (lane>>3)) * 8;                  // xor-swizzled 16B chunk
  const u16* Ks0 = QKVg + qkbase + 1024 + (size_t)sr0*3072 + sg;
  const u16* Ks1 = QKVg + qkbase + 1024 + (size_t)sr1*3072 + sg;
  const u16* Vs0 = VTg + vbase + (size_t)sr0*Nl + sg;
  const u16* Vs1 = VTg + vbase + (size_t)sr1*Nl + sg;

  f32x4 oacc[4];
  #pragma unroll
  for (int nt = 0; nt < 4; nt++) oacc[nt] = f32x4{0.f,0.f,0.f,0.f};
  float mrow = -1e30f, lrow = 0.f;

  auto stage = [&](int kt, int p) {
    const size_t ko = (size_t)kt * 64;
    gload_lds16(Ks0 + ko*3072, &Kt[p][si0*512]);
    gload_lds16(Ks1 + ko*3072, &Kt[p][si1*512]);
    gload_lds16(Vs0 + ko,      &Vt[p][si0*512]);
    gload_lds16(Vs1 + ko,      &Vt[p][si1*512]);
  };
  stage(0, 0);

  for (int kt = 0; kt <= qt; kt++) {
    const int p = kt & 1;
    __syncthreads();                 // drains my DMA, syncs all waves
    if (kt < qt) stage(kt+1, p^1);   // prefetch overlaps compute below

    // S^T = K Qt : per nt tile, rows key=nt*16.., cols q
    f32x4 st[4];
    #pragma unroll
    for (int nt = 0; nt < 4; nt++) {
      int key = nt*16 + c16, x = key & 7;
      short8 a0 = *(const short8*)(&Kt[p][key*64 + ((quad    )^x)*8]);
      short8 a1 = *(const short8*)(&Kt[p][key*64 + ((quad + 4)^x)*8]);
      f32x4 s = f32x4{0.f,0.f,0.f,0.f};
      s = __builtin_amdgcn_mfma_f32_16x16x32_bf16(a0, bq0, s, 0, 0, 0);
      s = __builtin_amdgcn_mfma_f32_16x16x32_bf16(a1, bq1, s, 0, 0, 0);
      st[nt] = s;
    }
    if (kt == qt) {
      const int k0 = kt*64;
      #pragma unroll
      for (int nt = 0; nt < 4; nt++)
        #pragma unroll
        for (int r = 0; r < 4; r++)
          if (k0 + nt*16 + quad*4 + r > qrow) st[nt][r] = -1e9f;
    }
    // online softmax per query column (lane-scalar state; quads replicate)
    float vmax = st[0][0];
    #pragma unroll
    for (int nt = 0; nt < 4; nt++)
      #pragma unroll
      for (int r = 0; r < 4; r++) vmax = fmaxf(vmax, st[nt][r]);
    vmax = fmaxf(vmax, __shfl_xor(vmax, 16));
    vmax = fmaxf(vmax, __shfl_xor(vmax, 32));
    float mn = fmaxf(mrow, vmax);
    float al = __builtin_amdgcn_exp2f(mrow - mn);
    mrow = mn;
    float ssum = 0.f;
    #pragma unroll
    for (int nt = 0; nt < 4; nt++)
      #pragma unroll
      for (int r = 0; r < 4; r++) {
        float e = __builtin_amdgcn_exp2f(st[nt][r] - mn);
        st[nt][r] = e; ssum += e;
      }
    ssum += __shfl_xor(ssum, 16);
    ssum += __shfl_xor(ssum, 32);
    lrow = lrow * al + ssum;
    #pragma unroll
    for (int nt = 0; nt < 4; nt++)
      #pragma unroll
      for (int r = 0; r < 4; r++) oacc[nt][r] *= al;
    // write P^T tile into per-wave [q][key] storage, packed 4-wide
    #pragma unroll
    for (int nt = 0; nt < 4; nt++) {
      u16x4 pv;
      #pragma unroll
      for (int r = 0; r < 4; r++) pv[r] = f2bf(st[nt][r]);
      *(u16x4*)(&Ps[wid][c16*68 + nt*16 + quad*4]) = pv;
    }
    // O^T += V^T P : A=V^T frag, B=P frag (reused across nt)
    short8 bp0 = *(const short8*)(&Ps[wid][c16*68 + quad*8]);
    short8 bp1 = *(const short8*)(&Ps[wid][c16*68 + 32 + quad*8]);
    #pragma unroll
    for (int nt = 0; nt < 4; nt++) {
      int dh = nt*16 + c16, x = dh & 7;
      short8 a0 = *(const short8*)(&Vt[p][dh*64 + ((quad    )^x)*8]);
      short8 a1 = *(const short8*)(&Vt[p][dh*64 + ((quad + 4)^x)*8]);
      oacc[nt] = __builtin_amdgcn_mfma_f32_16x16x32_bf16(a0, bp0, oacc[nt], 0, 0, 0);
      oacc[nt] = __builtin_amdgcn_mfma_f32_16x16x32_bf16(a1, bp1, oacc[nt], 0, 0, 0);
    }
  }
  const float rl = 1.f / lrow;
  #pragma unroll
  for (int nt = 0; nt < 4; nt++) {
    u16x4 o;
    #pragma unroll
    for (int r = 0; r < 4; r++) o[r] = f2bf(oacc[nt][r] * rl);
    *(u16x4*)(Og + (size_t)(b*Nl + qrow)*1024 + h*64 + nt*16 + quad*4) = o;
  }
}

// ---------------- Gram matrix of the 3 (coarse) Y tensors over the repeat map ----------
__global__ __launch_bounds__(256) void gram_k(const float* __restrict__ Y0, const float* __restrict__ Y1,
                                              const float* __restrict__ Y2, float* __restrict__ G) {
  float a[6] = {0,0,0,0,0,0};
  for (int i = blockIdx.x*256 + threadIdx.x; i < CNT; i += gridDim.x*256) {
    int d = i & 1023; int n = (i >> 10) & (N_-1); int b = i >> 21;
    float y0 = Y0[i];
    float y1 = Y1[(((size_t)b*(N_/2) + (n>>1)) << 10) + d];
    float y2 = Y2[(((size_t)b*(N_/4) + (n>>2)) << 10) + d];
    a[0] += y0*y0; a[1] += y0*y1; a[2] += y0*y2;
    a[3] += y1*y1; a[4] += y1*y2; a[5] += y2*y2;
  }
  __shared__ float red[4][6];
  const int lane = threadIdx.x & 63, wid = threadIdx.x >> 6;
  #pragma unroll
  for (int t = 0; t < 6; t++) {
    float v = a[t];
    v += __shfl_xor(v, 1);  v += __shfl_xor(v, 2);  v += __shfl_xor(v, 4);
    v += __shfl_xor(v, 8);  v += __shfl_xor(v, 16); v += __shfl_xor(v, 32);
    a[t] = v;
  }
  if (lane == 0)
    #pragma unroll
    for (int t = 0; t < 6; t++) red[wid][t] = a[t];
  __syncthreads();
  if (threadIdx.x < 6)
    atomicAdd(&G[threadIdx.x], red[0][threadIdx.x] + red[1][threadIdx.x] +
                               red[2][threadIdx.x] + red[3][threadIdx.x]);
}

__global__ void zero_k(float* p) { if (threadIdx.x < 64) p[threadIdx.x] = 0.f; }

// ---------------- Nash iterations + aux loss + both Sinkhorns (scalar) ----------------
__global__ void head_k(float* SC, const float* __restrict__ agg, const float* __restrict__ mA,
                       const float* __restrict__ mF, float* __restrict__ aux_out) {
  if (threadIdx.x != 0 || blockIdx.x != 0) return;
  float G[6];
  for (int t = 0; t < 6; t++) G[t] = SC[t];
  const int gi[3][3] = {{0,1,2},{1,3,4},{2,4,5}};
  float a[3] = {agg[0], agg[1], agg[2]};
  float w[3];
  {
    float m = fmaxf(a[0], fmaxf(a[1], a[2])); float s = 0.f;
    for (int l = 0; l < 3; l++) { w[l] = expf(a[l]-m); s += w[l]; }
    for (int l = 0; l < 3; l++) w[l] /= s;
  }
  const float inv = 1.f / (float)CNT;
  for (int it = 0; it < 3; it++) {
    float q = 0.f;
    for (int l = 0; l < 3; l++) for (int m2 = 0; m2 < 3; m2++) q += w[l]*w[m2]*G[gi[l][m2]];
    float z[3];
    for (int l = 0; l < 3; l++) {
      float dot = w[0]*G[gi[l][0]] + w[1]*G[gi[l][1]] + w[2]*G[gi[l][2]];
      z[l] = a[l] - (G[gi[l][l]] - 2.f*dot + q) * inv;
    }
    float m = fmaxf(z[0], fmaxf(z[1], z[2])); float s = 0.f;
    for (int l = 0; l < 3; l++) { w[l] = expf(z[l]-m); s += w[l]; }
    for (int l = 0; l < 3; l++) w[l] /= s;
  }
  SC[6] = w[0]; SC[7] = w[1]; SC[8] = w[2];
  aux_out[0] = w[0]*logf(w[0]*3.f + 1e-9f) + w[1]*logf(w[1]*3.f + 1e-9f) + w[2]*logf(w[2]*3.f + 1e-9f);
  for (int which = 0; which < 2; which++) {
    const float* Lg = which ? mF : mA;
    float M0 = expf(Lg[0]), M1 = expf(Lg[1]), M2 = expf(Lg[2]), M3 = expf(Lg[3]);
    for (int i2 = 0; i2 < 10; i2++) {
      float r0 = M0+M1, r1 = M2+M3; M0 /= r0; M1 /= r0; M2 /= r1; M3 /= r1;
      float c0 = M0+M2, c1 = M1+M3; M0 /= c0; M2 /= c0; M1 /= c1; M3 /= c1;
    }
    SC[9 + which*2] = M0; SC[10 + which*2] = M1;
  }
}

// ---------------- x1 = P00*x + P01*sum_l w_l * Y_l(upsampled) ----------------
__global__ __launch_bounds__(256) void mix1_k(const float* __restrict__ x, const float* __restrict__ Y0,
                                              const float* __restrict__ Y1, const float* __restrict__ Y2,
                                              const float* __restrict__ SC, float* __restrict__ x1) {
  const float w0 = SC[6], w1 = SC[7], w2 = SC[8], p0 = SC[9], p1 = SC[10];
  for (int i = blockIdx.x*256 + threadIdx.x; i < CNT; i += gridDim.x*256) {
    int d = i & 1023; int n = (i >> 10) & (N_-1); int b = i >> 21;
    float y = w0 * Y0[i]
            + w1 * Y1[(((size_t)b*(N_/2) + (n>>1)) << 10) + d]
            + w2 * Y2[(((size_t)b*(N_/4) + (n>>2)) << 10) + d];
    x1[i] = p0 * x[i] + p1 * y;
  }
}

// ---------------- h = silu(gu[:, :2816]) * gu[:, 2816:], 4-wide ----------------
__global__ __launch_bounds__(256) void silumul_k(const u16* __restrict__ gu, u16* __restrict__ h) {
  const int total4 = 4096 * 704;  // 4096 rows x 2816/4
  for (int t = blockIdx.x*256 + threadIdx.x; t < total4; t += gridDim.x*256) {
    int row = t / 704, c4 = (t - row*704) * 4;
    u16x4 g4 = *(const u16x4*)(gu + (size_t)row*5632 + c4);
    u16x4 u4 = *(const u16x4*)(gu + (size_t)row*5632 + 2816 + c4);
    u16x4 o;
    #pragma unroll
    for (int j = 0; j < 4; j++) {
      float gv = bf2f(g4[j]), uv = bf2f(u4[j]);
      o[j] = f2bf(gv / (1.f + __expf(-gv)) * uv);
    }
    *(u16x4*)(h + (size_t)row*2816 + c4) = o;
  }
}

__global__ __launch_bounds__(256) void final_k(const float* __restrict__ x1, const float* __restrict__ ffn,
                                               const float* __restrict__ SC, float* __restrict__ out) {
  const float q0 = SC[11], q1 = SC[12];
  for (int i = blockIdx.x*256 + threadIdx.x; i < CNT; i += gridDim.x*256)
    out[i] = q0 * x1[i] + q1 * ffn[i];
}

// ================================ host launcher ================================
extern "C" void kernel_launch(void* const* d_in, const int* in_sizes, int n_in,
                              void* d_out, int out_size, void* d_ws, size_t ws_size,
                              hipStream_t stream) {
  (void)in_sizes; (void)n_in; (void)out_size; (void)ws_size;
  const float* x    = (const float*)d_in[0];
  const float* nw1  = (const float*)d_in[1];
  const float* nw2  = (const float*)d_in[2];
  const float* Wdec = (const float*)d_in[3];
  const float* Wq   = (const float*)d_in[4];
  const float* Wk   = (const float*)d_in[5];
  const float* Wv   = (const float*)d_in[6];
  const float* Wo   = (const float*)d_in[7];
  const float* agg  = (const float*)d_in[8];
  const float* Wg   = (const float*)d_in[9];
  const float* Wu   = (const float*)d_in[10];
  const float* Wdn  = (const float*)d_in[11];
  const float* mA   = (const float*)d_in[12];
  const float* mF   = (const float*)d_in[13];
  float* out = (float*)d_out;

  char* ws = (char*)d_ws;
  size_t off = 0;
  auto take = [&](size_t b) { size_t r = off; off += (b + 255) & ~(size_t)255; return r; };

  u16* A_wp  = (u16*)(ws + take((size_t)9216*1024*2));   // [Wq0;Wk0;Wv][Wq1;Wk1;Wv][Wq2;Wk2;Wv] (T)
  u16* WdecB = (u16*)(ws + take((size_t)3*1024*1024*2)); // plain bf16 Wdec
  u16* Wqkv  = (u16*)(ws + take((size_t)9216*1024*2));   // fused (Wdec@[Wq|Wk|Wv])^T per level
  u16* BTgu  = (u16*)(ws + take((size_t)5632*1024*2));   // [WgT; WuT]
  u16* WdnT  = (u16*)(ws + take((size_t)HIDP*1024*2));
  u16* WoT   = (u16*)(ws + take((size_t)1024*1024*2));
  u16* xn_all = (u16*)(ws + take((size_t)7168*1024*2));  // rows: 4096 L0 | 2048 L1 | 1024 L2
  float* x1  = (float*)(ws + take((size_t)CNT*4));
  float* SCb = (float*)(ws + take(256));
  char*  big = ws + take(102760448);                     // union region
  // attention phase
  u16*   QKV   = (u16*)big;                              // [7168, 3072] bf16
  u16*   VTa   = (u16*)(big + 44040192);                 // per-level [b][c][Nl]
  u16*   Ob    = (u16*)(big + 58720256);                 // [7168, 1024] bf16
  float* YC    = (float*)(big + 73400320);               // [7168, 1024] fp32
  // FFN phase (attention buffers dead by then)
  u16*   gu    = (u16*)big;                              // [4096, 5632]
  u16*   hbuf  = (u16*)(big + 46137344);                 // [4096, 2816]
  float* ffn   = (float*)(big + 69206016);               // [4096, 1024]

  const int rowbase[3] = {0, 4096, 6144};
  const int Nl[3] = {2048, 1024, 512};
  const size_t vtoff[3] = {0, (size_t)2*1024*2048, (size_t)2*1024*2048 + (size_t)2*1024*1024};

  dim3 blk(256);
  const int BIG = 1 << 30;

  // ---- weight prep ----
  conv_k<<<2048, blk, 0, stream>>>(Wdec, WdecB, 3*1024*1024);
  for (int l = 0; l < 3; l++) {
    twconv_k<<<dim3(32,32), blk, 0, stream>>>(Wq + (size_t)l*1048576, A_wp + (size_t)(l*3072 + 0)*1024,
                                              1024,1024,1024,1024, 0.125f * LOG2E);
    twconv_k<<<dim3(32,32), blk, 0, stream>>>(Wk + (size_t)l*1048576, A_wp + (size_t)(l*3072 + 1024)*1024,
                                              1024,1024,1024,1024, 1.f);
    twconv_k<<<dim3(32,32), blk, 0, stream>>>(Wv, A_wp + (size_t)(l*3072 + 2048)*1024,
                                              1024,1024,1024,1024, 1.f);
  }
  twconv_k<<<dim3(32,32), blk, 0, stream>>>(Wo, WoT, 1024,1024,1024,1024, 1.f);
  twconv_k<<<dim3(88,32), blk, 0, stream>>>(Wg,  BTgu,                     1024, HID_, 1024, HIDP, 1.f);
  twconv_k<<<dim3(88,32), blk, 0, stream>>>(Wu,  BTgu + (size_t)HIDP*1024, 1024, HID_, 1024, HIDP, 1.f);
  twconv_k<<<dim3(32,88), blk, 0, stream>>>(Wdn, WdnT, HID_, 1024, HIDP, 1024, 1.f);
  // fused QKV weights: C = A_wp x WdecB_l^T  ->  F_l^T [3072,1024] per level
  gemm_bt<<<dim3(8, 72), blk, 0, stream>>>(A_wp, WdecB, Wqkv, 1024, 1024, 1, 24, 48, 1024u*1024u);

  // ---- attention branch ----
  rmsnorm_k<<<4096, blk, 0, stream>>>(x, nw1, xn_all);
  pool_k<<<1024, blk, 0, stream>>>(xn_all,                      xn_all + (size_t)4096*1024, 1024);
  pool_k<<<512,  blk, 0, stream>>>(xn_all + (size_t)4096*1024,  xn_all + (size_t)6144*1024, 512);

  gemm_bt<<<dim3(24, 56), blk, 0, stream>>>(xn_all, Wqkv, QKV, 3072, 1024, 1, 32, 48, 3072u*1024u);
  for (int l = 0; l < 3; l++)
    vtrans_k<<<dim3(Nl[l]/32, 32, B_), blk, 0, stream>>>(QKV + (size_t)rowbase[l]*3072 + 2048,
                                                         VTa + vtoff[l], Nl[l]);
  for (int l = 0; l < 3; l++)
    flash_k<<<dim3(Nl[l]/64, B_*H_), blk, 0, stream>>>(QKV + (size_t)rowbase[l]*3072,
                                                       VTa + vtoff[l],
                                                       Ob + (size_t)rowbase[l]*1024, Nl[l]);
  gemm_bt<<<dim3(8, 56), blk, 0, stream>>>(Ob, WoT, YC, 1024, 1024, 0, BIG, BIG, 0u);

  float* YC1 = YC + (size_t)4096*1024;
  float* YC2 = YC + (size_t)6144*1024;
  zero_k<<<1, 64, 0, stream>>>(SCb);
  gram_k<<<1024, blk, 0, stream>>>(YC, YC1, YC2, SCb);
  head_k<<<1, 64, 0, stream>>>(SCb, agg, mA, mF, out + CNT);
  mix1_k<<<2048, blk, 0, stream>>>(x, YC, YC1, YC2, SCb, x1);

  // ---- FFN branch ----
  rmsnorm_k<<<4096, blk, 0, stream>>>(x1, nw2, xn_all);
  gemm_bt<<<dim3(44, 32), blk, 0, stream>>>(xn_all, BTgu, gu, 5632, 1024, 1, BIG, BIG, 0u);
  silumul_k<<<2048, blk, 0, stream>>>(gu, hbuf);
  gemm_bt<<<dim3(8, 32), blk, 0, stream>>>(hbuf, WdnT, ffn, 1024, HIDP, 0, BIG, BIG, 0u);
  final_k<<<2048, blk, 0, stream>>>(x1, ffn, SCb, out);
}

// Round 4
// 562.450 us; speedup vs baseline: 1.7555x; 1.2180x over previous
//
#include <hip/hip_runtime.h>
#include <stdint.h>

// MAHA decoder block, MI355X/gfx950. Round 4 (= Round 3 + compile fix).
// B=2, N=2048, D=1024, H=16(dh=64), L=3, R=2, HID=2734(->2816), fp32 I/O.
// ~183 MB of d_ws.

#define B_   2
#define N_   2048
#define D_   1024
#define H_   16
#define DH_  64
#define HID_ 2734
#define HIDP 2816
#define CNT  (B_*N_*D_)   // 4194304
#define LOG2E 1.4426950408889634f

typedef unsigned short u16;
typedef __attribute__((ext_vector_type(8))) short short8;
typedef __attribute__((ext_vector_type(4))) float f32x4;
typedef __attribute__((ext_vector_type(4))) uint16_t u16x4;

__device__ __forceinline__ u16 f2bf(float f) {
  uint32_t u = __builtin_bit_cast(uint32_t, f);
  u += 0x7fffu + ((u >> 16) & 1u);          // RNE
  return (u16)(u >> 16);
}
__device__ __forceinline__ float bf2f(u16 h) {
  uint32_t u = ((uint32_t)h) << 16;
  return __builtin_bit_cast(float, u);
}
__device__ __forceinline__ uint32_t pkbf(float a, float b) {
  return (uint32_t)f2bf(a) | ((uint32_t)f2bf(b) << 16);
}
__device__ __forceinline__ void gload_lds16(const void* g, void* l) {
  __builtin_amdgcn_global_load_lds(
      (const __attribute__((address_space(1))) uint32_t*)g,
      (__attribute__((address_space(3))) uint32_t*)l, 16, 0, 0);
}

// ---------------- fp32 [K,N] -> bf16 BT [NP,KP] transpose+convert (+scale, zero-pad) ----
__global__ __launch_bounds__(256) void twconv_k(const float* __restrict__ W, u16* __restrict__ BT,
                                                int K, int N, int KP, int NP, float scale) {
  __shared__ float t[32][33];
  const int tx = threadIdx.x & 31, ty = threadIdx.x >> 5;   // 32 x 8
  const int nb = blockIdx.x * 32, kb = blockIdx.y * 32;
  #pragma unroll
  for (int i = 0; i < 4; i++) {
    int k = kb + ty + i*8, n = nb + tx;
    t[ty + i*8][tx] = (k < K && n < N) ? W[(size_t)k * N + n] * scale : 0.f;
  }
  __syncthreads();
  #pragma unroll
  for (int i = 0; i < 4; i++) {
    int n = nb + ty + i*8, k = kb + tx;
    if (n < NP && k < KP) BT[(size_t)n * KP + k] = f2bf(t[tx][ty + i*8]);
  }
}

// ---------------- plain fp32 -> bf16 convert ----------------
__global__ __launch_bounds__(256) void conv_k(const float* __restrict__ in, u16* __restrict__ out, int total) {
  for (int i = blockIdx.x*256 + threadIdx.x; i < total; i += gridDim.x*256)
    out[i] = f2bf(in[i]);
}

// ---------------- RMSNorm: fp32 row [rows, D] -> bf16 ----------------
__global__ __launch_bounds__(256) void rmsnorm_k(const float* __restrict__ x,
                                                 const float* __restrict__ w,
                                                 u16* __restrict__ out) {
  const int row = blockIdx.x;
  const float* xr = x + (size_t)row * D_;
  float ss = 0.f;
  #pragma unroll
  for (int i = 0; i < 4; i++) { float v = xr[threadIdx.x + i*256]; ss += v*v; }
  ss += __shfl_xor(ss, 1);  ss += __shfl_xor(ss, 2);  ss += __shfl_xor(ss, 4);
  ss += __shfl_xor(ss, 8);  ss += __shfl_xor(ss, 16); ss += __shfl_xor(ss, 32);
  __shared__ float red[4];
  if ((threadIdx.x & 63) == 0) red[threadIdx.x >> 6] = ss;
  __syncthreads();
  float sc = rsqrtf((red[0]+red[1]+red[2]+red[3]) * (1.f/D_) + 1e-6f);
  #pragma unroll
  for (int i = 0; i < 4; i++) {
    int c = threadIdx.x + i*256;
    out[(size_t)row * D_ + c] = f2bf(xr[c] * w[c] * sc);
  }
}

// ---------------- avg-pool by 2 along seq (bf16), 4-wide; No = 1<<lg ----------------
__global__ __launch_bounds__(256) void pool_k(const u16* __restrict__ in, u16* __restrict__ out, int lg) {
  const int No = 1 << lg;
  const int total4 = B_ * No * 256;
  for (int i = blockIdx.x*256 + threadIdx.x; i < total4; i += gridDim.x*256) {
    int d4 = i & 255; int j = (i >> 8) & (No - 1); int b = i >> (8 + lg);
    size_t src = ((size_t)(b*2*No + 2*j) << 10) + d4*4;
    u16x4 a = *(const u16x4*)(in + src);
    u16x4 c = *(const u16x4*)(in + src + 1024);
    u16x4 o;
    #pragma unroll
    for (int t = 0; t < 4; t++) o[t] = f2bf(0.5f * (bf2f(a[t]) + bf2f(c[t])));
    *(u16x4*)(out + (size_t)i*4) = o;
  }
}

// ---------------- MFMA GEMM, C = A[M,K] * BT[N,K]^T; block = MT*32 x 128 ----------------
// MODE: 1 = bf16 store, 2 = fp32 out = SCp[11]*X1 + SCp[12]*acc
// Optional per-row-range BT selection: level = (y>=t2)?2:(y>=t1)?1:0; BT += level*bt_stride.
template<int MT, int MODE>
__global__ __launch_bounds__(256) void gemm_t(const u16* __restrict__ A, const u16* __restrict__ BT,
                                              void* __restrict__ Cv, const float* __restrict__ X1,
                                              const float* __restrict__ SCp,
                                              int N, int K, int t1, int t2, unsigned int bt_stride) {
  __shared__ __align__(16) u16 As[MT*32*32];
  __shared__ __align__(16) u16 Bs[128*32];
  const int tid = threadIdx.x;
  const int lane = tid & 63, wid = tid >> 6;
  const int quad = lane >> 4, c16 = lane & 15;
  const int y = blockIdx.y;
  const int m0 = y * (MT*32), n0 = blockIdx.x * 128;
  const int wm = wid >> 1, wn = wid & 1;
  const int level = (y >= t2) ? 2 : ((y >= t1) ? 1 : 0);
  BT += (size_t)level * bt_stride;

  f32x4 acc[MT][4];
  #pragma unroll
  for (int i = 0; i < MT; i++)
    #pragma unroll
    for (int j = 0; j < 4; j++) acc[i][j] = f32x4{0.f,0.f,0.f,0.f};

  const int srow = lane >> 2;
  const int schunk = lane & 3;
  for (int k0 = 0; k0 < K; k0 += 32) {
    #pragma unroll
    for (int t = 0; t < MT/2; t++) {
      int idx = wid*(MT/2) + t;
      int row = idx*16 + srow;
      int g = (schunk ^ ((row >> 1) & 3)) * 8;
      gload_lds16(A + (size_t)(m0+row)*K + k0 + g, As + idx*512);
    }
    #pragma unroll
    for (int t = 0; t < 2; t++) {
      int idx = wid*2 + t;
      int row = idx*16 + srow;
      int g = (schunk ^ ((row >> 1) & 3)) * 8;
      gload_lds16(BT + (size_t)(n0+row)*K + k0 + g, Bs + idx*512);
    }
    __syncthreads();
    short8 af[MT], bfr[4];
    #pragma unroll
    for (int mt = 0; mt < MT; mt++) {
      int ar = wm*(MT*16) + mt*16 + c16;
      af[mt]  = *(const short8*)(As + ar*32 + (quad ^ ((ar>>1)&3))*8);
    }
    #pragma unroll
    for (int nt = 0; nt < 4; nt++) {
      int br = wn*64 + nt*16 + c16;
      bfr[nt] = *(const short8*)(Bs + br*32 + (quad ^ ((br>>1)&3))*8);
    }
    #pragma unroll
    for (int mt = 0; mt < MT; mt++)
      #pragma unroll
      for (int nt = 0; nt < 4; nt++)
        acc[mt][nt] = __builtin_amdgcn_mfma_f32_16x16x32_bf16(af[mt], bfr[nt], acc[mt][nt], 0, 0, 0);
    __syncthreads();
  }
  if (MODE == 1) {
    u16* C = (u16*)Cv;
    #pragma unroll
    for (int mt = 0; mt < MT; mt++)
      #pragma unroll
      for (int nt = 0; nt < 4; nt++)
        #pragma unroll
        for (int r = 0; r < 4; r++) {
          int row = m0 + wm*(MT*16) + mt*16 + quad*4 + r;
          int col = n0 + wn*64 + nt*16 + c16;
          C[(size_t)row * N + col] = f2bf(acc[mt][nt][r]);
        }
  } else {
    float* C = (float*)Cv;
    const float q0 = SCp[11], q1 = SCp[12];
    #pragma unroll
    for (int mt = 0; mt < MT; mt++)
      #pragma unroll
      for (int nt = 0; nt < 4; nt++)
        #pragma unroll
        for (int r = 0; r < 4; r++) {
          int row = m0 + wm*(MT*16) + mt*16 + quad*4 + r;
          int col = n0 + wn*64 + nt*16 + c16;
          size_t o = (size_t)row * N + col;
          C[o] = q0 * X1[o] + q1 * acc[mt][nt][r];
        }
  }
}

// ---------------- bf16 transpose: V part of QKV -> VT [b][c][n] ----------------
__global__ __launch_bounds__(256) void vtrans_k(const u16* __restrict__ in, u16* __restrict__ out, int Nl) {
  __shared__ u16 t[32][33];
  const int n0 = blockIdx.x*32, c0 = blockIdx.y*32, b = blockIdx.z;
  const int tx = threadIdx.x & 31, ty = threadIdx.x >> 5;
  #pragma unroll
  for (int i = 0; i < 4; i++)
    t[ty + i*8][tx] = in[(size_t)(b*Nl + n0 + ty + i*8)*3072 + c0 + tx];
  __syncthreads();
  #pragma unroll
  for (int i = 0; i < 4; i++)
    out[(size_t)(b*1024 + c0 + ty + i*8)*Nl + n0 + tx] = t[tx][ty + i*8];
}

// ---------------- MFMA flash attention, all levels merged, no-max online softmax ----
// 896 blocks: L0 512 (qt 15..0), L1 256 (qt 7..0), L2 128 (qt 3..0); 128 q per block,
// 32 q per wave; K-tiles of 64 keys, double-buffered direct-to-LDS staging.
__global__ __launch_bounds__(256) void flash_k(const u16* __restrict__ QKVg,
                                               const u16* __restrict__ VTg,
                                               u16* __restrict__ Og) {
  __shared__ __align__(16) u16 Kt[2][64*64];
  __shared__ __align__(16) u16 Vt[2][64*64];
  __shared__ __align__(16) u16 Ps[4][32*68];
  const int tid = threadIdx.x, lane = tid & 63, wid = tid >> 6;
  const int quad = lane >> 4, c16 = lane & 15;
  const int id = blockIdx.x;
  int qt, bh, Nl, rowbase; size_t vtoff;
  if (id < 512)      { qt = 15 - (id >> 5);            bh = id & 31;  Nl = 2048; rowbase = 0;    vtoff = 0; }
  else if (id < 768) { int t2 = id - 512; qt = 7 - (t2 >> 5); bh = t2 & 31; Nl = 1024; rowbase = 4096; vtoff = 4194304; }
  else               { int t2 = id - 768; qt = 3 - (t2 >> 5); bh = t2 & 31; Nl = 512;  rowbase = 6144; vtoff = 6291456; }
  const int b = bh >> 4, h = bh & 15;
  const u16* QK = QKVg + ((size_t)(rowbase + b*Nl)) * 3072 + h*64;
  u16* Ow = Og + ((size_t)(rowbase + b*Nl)) * 1024 + h*64;
  const u16* VT = VTg + vtoff + ((size_t)b*1024 + h*64) * (size_t)Nl;

  const int q0r = qt*128 + wid*32;
  short8 bq[2][2];
  #pragma unroll
  for (int qh = 0; qh < 2; qh++) {
    const u16* qp = QK + (size_t)(q0r + qh*16 + c16)*3072 + quad*8;
    bq[qh][0] = *(const short8*)qp;
    bq[qh][1] = *(const short8*)(qp + 32);
  }
  const int si0 = wid*2, si1 = si0 + 1;
  const int sr0 = si0*8 + (lane>>3), sr1 = si1*8 + (lane>>3);
  const int sg  = ((lane&7) ^ (lane>>3)) * 8;
  const u16* Ks0 = QK + 1024 + (size_t)sr0*3072 + sg;
  const u16* Ks1 = QK + 1024 + (size_t)sr1*3072 + sg;
  const u16* Vs0 = VT + (size_t)sr0*Nl + sg;
  const u16* Vs1 = VT + (size_t)sr1*Nl + sg;

  f32x4 oacc[2][4];
  f32x4 lacc[2];
  #pragma unroll
  for (int qh = 0; qh < 2; qh++) {
    lacc[qh] = f32x4{0.f,0.f,0.f,0.f};
    #pragma unroll
    for (int nt = 0; nt < 4; nt++) oacc[qh][nt] = f32x4{0.f,0.f,0.f,0.f};
  }

  auto stage = [&](int kt, int p) {
    const size_t ko = (size_t)kt * 64;
    gload_lds16(Ks0 + ko*3072, &Kt[p][si0*512]);
    gload_lds16(Ks1 + ko*3072, &Kt[p][si1*512]);
    gload_lds16(Vs0 + ko,      &Vt[p][si0*512]);
    gload_lds16(Vs1 + ko,      &Vt[p][si1*512]);
  };
  const int kmax_w = 2*qt + (wid >> 1);   // waves 0,1 skip the last (fully masked) tile
  const int ktot   = 2*qt + 2;
  stage(0, 0);

  for (int kt = 0; kt < ktot; kt++) {
    const int p = kt & 1;
    __syncthreads();
    if (kt + 1 < ktot) stage(kt+1, p^1);
    if (kt > kmax_w) continue;

    // S^T = K Q^T  (A = K[key][dh], B = Q^T) -> st[qh][nt] C-layout: row=key, col=q
    f32x4 st[2][4];
    #pragma unroll
    for (int nt = 0; nt < 4; nt++) {
      int key = nt*16 + c16, x = key & 7;
      short8 a0 = *(const short8*)(&Kt[p][key*64 + ((quad    ) ^ x)*8]);
      short8 a1 = *(const short8*)(&Kt[p][key*64 + ((quad + 4) ^ x)*8]);
      #pragma unroll
      for (int qh = 0; qh < 2; qh++) {
        f32x4 s = f32x4{0.f,0.f,0.f,0.f};
        s = __builtin_amdgcn_mfma_f32_16x16x32_bf16(a0, bq[qh][0], s, 0, 0, 0);
        s = __builtin_amdgcn_mfma_f32_16x16x32_bf16(a1, bq[qh][1], s, 0, 0, 0);
        st[qh][nt] = s;
      }
    }
    // exp2 (scores pre-scaled by 1/8*log2e in Wq; small => no max needed), mask diag
    if (kt >= 2*qt) {
      const int kb = kt*64;
      #pragma unroll
      for (int qh = 0; qh < 2; qh++) {
        const int qr = q0r + qh*16 + c16;
        #pragma unroll
        for (int nt = 0; nt < 4; nt++) {
          #pragma unroll
          for (int r = 0; r < 4; r++) {
            float e = __builtin_amdgcn_exp2f(st[qh][nt][r]);
            st[qh][nt][r] = (kb + nt*16 + quad*4 + r <= qr) ? e : 0.f;
          }
          lacc[qh] += st[qh][nt];
        }
      }
    } else {
      #pragma unroll
      for (int qh = 0; qh < 2; qh++)
        #pragma unroll
        for (int nt = 0; nt < 4; nt++) {
          #pragma unroll
          for (int r = 0; r < 4; r++) st[qh][nt][r] = __builtin_amdgcn_exp2f(st[qh][nt][r]);
          lacc[qh] += st[qh][nt];
        }
    }
    // P^T -> per-wave LDS [q][key]
    #pragma unroll
    for (int qh = 0; qh < 2; qh++) {
      const int prow = qh*16 + c16;
      #pragma unroll
      for (int nt = 0; nt < 4; nt++) {
        uint2 pk;
        pk.x = pkbf(st[qh][nt][0], st[qh][nt][1]);
        pk.y = pkbf(st[qh][nt][2], st[qh][nt][3]);
        *(uint2*)(&Ps[wid][prow*68 + nt*16 + quad*4]) = pk;
      }
    }
    short8 bp[2][2];
    #pragma unroll
    for (int qh = 0; qh < 2; qh++) {
      bp[qh][0] = *(const short8*)(&Ps[wid][(qh*16 + c16)*68 +      quad*8]);
      bp[qh][1] = *(const short8*)(&Ps[wid][(qh*16 + c16)*68 + 32 + quad*8]);
    }
    // O^T += V^T P
    #pragma unroll
    for (int nt = 0; nt < 4; nt++) {
      int dh = nt*16 + c16, x = dh & 7;
      short8 a0 = *(const short8*)(&Vt[p][dh*64 + ((quad    ) ^ x)*8]);
      short8 a1 = *(const short8*)(&Vt[p][dh*64 + ((quad + 4) ^ x)*8]);
      #pragma unroll
      for (int qh = 0; qh < 2; qh++) {
        oacc[qh][nt] = __builtin_amdgcn_mfma_f32_16x16x32_bf16(a0, bp[qh][0], oacc[qh][nt], 0, 0, 0);
        oacc[qh][nt] = __builtin_amdgcn_mfma_f32_16x16x32_bf16(a1, bp[qh][1], oacc[qh][nt], 0, 0, 0);
      }
    }
  }
  #pragma unroll
  for (int qh = 0; qh < 2; qh++) {
    float ls = lacc[qh][0] + lacc[qh][1] + lacc[qh][2] + lacc[qh][3];
    ls += __shfl_xor(ls, 16);
    ls += __shfl_xor(ls, 32);
    const float rl = 1.f / ls;
    #pragma unroll
    for (int nt = 0; nt < 4; nt++) {
      uint2 o;
      o.x = pkbf(oacc[qh][nt][0]*rl, oacc[qh][nt][1]*rl);
      o.y = pkbf(oacc[qh][nt][2]*rl, oacc[qh][nt][3]*rl);
      *(uint2*)(Ow + (size_t)(q0r + qh*16 + c16)*1024 + nt*16 + quad*4) = o;
    }
  }
}

// ---------------- Gram matrix over repeat map (bf16 Y), 4-wide ----------------
__global__ __launch_bounds__(256) void gram_k(const u16* __restrict__ Y0, const u16* __restrict__ Y1,
                                              const u16* __restrict__ Y2, float* __restrict__ G) {
  float a[6] = {0,0,0,0,0,0};
  const int total4 = CNT/4;
  for (int i = blockIdx.x*256 + threadIdx.x; i < total4; i += gridDim.x*256) {
    int d4 = i & 255; int n = (i >> 8) & (N_-1); int b = i >> 19;
    u16x4 y0v = *(const u16x4*)(Y0 + (size_t)i*4);
    u16x4 y1v = *(const u16x4*)(Y1 + (((size_t)(b*1024 + (n>>1))) << 10) + d4*4);
    u16x4 y2v = *(const u16x4*)(Y2 + (((size_t)(b*512  + (n>>2))) << 10) + d4*4);
    #pragma unroll
    for (int t = 0; t < 4; t++) {
      float y0 = bf2f(y0v[t]), y1 = bf2f(y1v[t]), y2 = bf2f(y2v[t]);
      a[0] += y0*y0; a[1] += y0*y1; a[2] += y0*y2;
      a[3] += y1*y1; a[4] += y1*y2; a[5] += y2*y2;
    }
  }
  __shared__ float red[4][6];
  const int lane = threadIdx.x & 63, wid = threadIdx.x >> 6;
  #pragma unroll
  for (int t = 0; t < 6; t++) {
    float v = a[t];
    v += __shfl_xor(v, 1);  v += __shfl_xor(v, 2);  v += __shfl_xor(v, 4);
    v += __shfl_xor(v, 8);  v += __shfl_xor(v, 16); v += __shfl_xor(v, 32);
    a[t] = v;
  }
  if (lane == 0)
    #pragma unroll
    for (int t = 0; t < 6; t++) red[wid][t] = a[t];
  __syncthreads();
  if (threadIdx.x < 6)
    atomicAdd(&G[threadIdx.x], red[0][threadIdx.x] + red[1][threadIdx.x] +
                               red[2][threadIdx.x] + red[3][threadIdx.x]);
}

__global__ void zero_k(float* p) { if (threadIdx.x < 64) p[threadIdx.x] = 0.f; }

// ---------------- Nash iterations + aux loss + both Sinkhorns (scalar) ----------------
__global__ void head_k(float* SC, const float* __restrict__ agg, const float* __restrict__ mA,
                       const float* __restrict__ mF, float* __restrict__ aux_out) {
  if (threadIdx.x != 0 || blockIdx.x != 0) return;
  float G[6];
  for (int t = 0; t < 6; t++) G[t] = SC[t];
  const int gi[3][3] = {{0,1,2},{1,3,4},{2,4,5}};
  float a[3] = {agg[0], agg[1], agg[2]};
  float w[3];
  {
    float m = fmaxf(a[0], fmaxf(a[1], a[2])); float s = 0.f;
    for (int l = 0; l < 3; l++) { w[l] = expf(a[l]-m); s += w[l]; }
    for (int l = 0; l < 3; l++) w[l] /= s;
  }
  const float inv = 1.f / (float)CNT;
  for (int it = 0; it < 3; it++) {
    float q = 0.f;
    for (int l = 0; l < 3; l++) for (int m2 = 0; m2 < 3; m2++) q += w[l]*w[m2]*G[gi[l][m2]];
    float z[3];
    for (int l = 0; l < 3; l++) {
      float dot = w[0]*G[gi[l][0]] + w[1]*G[gi[l][1]] + w[2]*G[gi[l][2]];
      z[l] = a[l] - (G[gi[l][l]] - 2.f*dot + q) * inv;
    }
    float m = fmaxf(z[0], fmaxf(z[1], z[2])); float s = 0.f;
    for (int l = 0; l < 3; l++) { w[l] = expf(z[l]-m); s += w[l]; }
    for (int l = 0; l < 3; l++) w[l] /= s;
  }
  SC[6] = w[0]; SC[7] = w[1]; SC[8] = w[2];
  aux_out[0] = w[0]*logf(w[0]*3.f + 1e-9f) + w[1]*logf(w[1]*3.f + 1e-9f) + w[2]*logf(w[2]*3.f + 1e-9f);
  for (int which = 0; which < 2; which++) {
    const float* Lg = which ? mF : mA;
    float M0 = expf(Lg[0]), M1 = expf(Lg[1]), M2 = expf(Lg[2]), M3 = expf(Lg[3]);
    for (int i2 = 0; i2 < 10; i2++) {
      float r0 = M0+M1, r1 = M2+M3; M0 /= r0; M1 /= r0; M2 /= r1; M3 /= r1;
      float c0 = M0+M2, c1 = M1+M3; M0 /= c0; M2 /= c0; M1 /= c1; M3 /= c1;
    }
    SC[9 + which*2] = M0; SC[10 + which*2] = M1;
  }
}

// ---------------- x1 = P00*x + P01*sum_l w_l * Y_l(upsampled), 4-wide ----------------
__global__ __launch_bounds__(256) void mix1_k(const float4* __restrict__ x, const u16* __restrict__ Y0,
                                              const u16* __restrict__ Y1, const u16* __restrict__ Y2,
                                              const float* __restrict__ SC, float4* __restrict__ x1) {
  const float w0 = SC[6], w1 = SC[7], w2 = SC[8], p0 = SC[9], p1 = SC[10];
  const int total4 = CNT/4;
  for (int i = blockIdx.x*256 + threadIdx.x; i < total4; i += gridDim.x*256) {
    int d4 = i & 255; int n = (i >> 8) & (N_-1); int b = i >> 19;
    u16x4 y0v = *(const u16x4*)(Y0 + (size_t)i*4);
    u16x4 y1v = *(const u16x4*)(Y1 + (((size_t)(b*1024 + (n>>1))) << 10) + d4*4);
    u16x4 y2v = *(const u16x4*)(Y2 + (((size_t)(b*512  + (n>>2))) << 10) + d4*4);
    float4 xv = x[i];
    float4 o;
    o.x = p0*xv.x + p1*(w0*bf2f(y0v[0]) + w1*bf2f(y1v[0]) + w2*bf2f(y2v[0]));
    o.y = p0*xv.y + p1*(w0*bf2f(y0v[1]) + w1*bf2f(y1v[1]) + w2*bf2f(y2v[1]));
    o.z = p0*xv.z + p1*(w0*bf2f(y0v[2]) + w1*bf2f(y1v[2]) + w2*bf2f(y2v[2]));
    o.w = p0*xv.w + p1*(w0*bf2f(y0v[3]) + w1*bf2f(y1v[3]) + w2*bf2f(y2v[3]));
    x1[i] = o;
  }
}

// ---------------- h = silu(gu[:, :2816]) * gu[:, 2816:], 4-wide ----------------
__global__ __launch_bounds__(256) void silumul_k(const u16* __restrict__ gu, u16* __restrict__ h) {
  const int total4 = 4096 * 704;
  for (int t = blockIdx.x*256 + threadIdx.x; t < total4; t += gridDim.x*256) {
    int row = t / 704, c4 = (t - row*704) * 4;
    u16x4 g4 = *(const u16x4*)(gu + (size_t)row*5632 + c4);
    u16x4 u4 = *(const u16x4*)(gu + (size_t)row*5632 + 2816 + c4);
    u16x4 o;
    #pragma unroll
    for (int j = 0; j < 4; j++) {
      float gv = bf2f(g4[j]), uv = bf2f(u4[j]);
      o[j] = f2bf(gv / (1.f + __expf(-gv)) * uv);
    }
    *(u16x4*)(h + (size_t)row*2816 + c4) = o;
  }
}

// ================================ host launcher ================================
extern "C" void kernel_launch(void* const* d_in, const int* in_sizes, int n_in,
                              void* d_out, int out_size, void* d_ws, size_t ws_size,
                              hipStream_t stream) {
  (void)in_sizes; (void)n_in; (void)out_size; (void)ws_size;
  const float* x    = (const float*)d_in[0];
  const float* nw1  = (const float*)d_in[1];
  const float* nw2  = (const float*)d_in[2];
  const float* Wdec = (const float*)d_in[3];
  const float* Wq   = (const float*)d_in[4];
  const float* Wk   = (const float*)d_in[5];
  const float* Wv   = (const float*)d_in[6];
  const float* Wo   = (const float*)d_in[7];
  const float* agg  = (const float*)d_in[8];
  const float* Wg   = (const float*)d_in[9];
  const float* Wu   = (const float*)d_in[10];
  const float* Wdn  = (const float*)d_in[11];
  const float* mA   = (const float*)d_in[12];
  const float* mF   = (const float*)d_in[13];
  float* out = (float*)d_out;

  char* ws = (char*)d_ws;
  size_t off = 0;
  auto take = [&](size_t b) { size_t r = off; off += (b + 255) & ~(size_t)255; return r; };

  u16* A_wp  = (u16*)(ws + take((size_t)9216*1024*2));
  u16* WdecB = (u16*)(ws + take((size_t)3*1024*1024*2));
  u16* Wqkv  = (u16*)(ws + take((size_t)9216*1024*2));
  u16* BTgu  = (u16*)(ws + take((size_t)5632*1024*2));
  u16* WdnT  = (u16*)(ws + take((size_t)HIDP*1024*2));
  u16* WoT   = (u16*)(ws + take((size_t)1024*1024*2));
  u16* xn_all = (u16*)(ws + take((size_t)7168*1024*2));
  float* x1  = (float*)(ws + take((size_t)CNT*4));
  float* SCb = (float*)(ws + take(256));
  char*  big = ws + take(88080384);
  // attention phase
  u16*   QKV   = (u16*)big;                              // [7168, 3072] bf16
  u16*   VTa   = (u16*)(big + 44040192);                 // per-level [b][1024][Nl]
  u16*   Ob    = (u16*)(big + 58720256);                 // [7168, 1024] bf16
  u16*   YC    = (u16*)(big + 73400320);                 // [7168, 1024] bf16
  // FFN phase aliases
  u16*   gu    = (u16*)big;                              // [4096, 5632]
  u16*   hbuf  = (u16*)(big + 46137344);                 // [4096, 2816]

  const int rowbase[3] = {0, 4096, 6144};
  const int Nl[3] = {2048, 1024, 512};
  const size_t vtoff[3] = {0, 4194304, 6291456};

  dim3 blk(256);
  const int BIG = 1 << 30;

  // ---- weight prep ----
  conv_k<<<2048, blk, 0, stream>>>(Wdec, WdecB, 3*1024*1024);
  for (int l = 0; l < 3; l++) {
    twconv_k<<<dim3(32,32), blk, 0, stream>>>(Wq + (size_t)l*1048576, A_wp + (size_t)(l*3072 + 0)*1024,
                                              1024,1024,1024,1024, 0.125f * LOG2E);
    twconv_k<<<dim3(32,32), blk, 0, stream>>>(Wk + (size_t)l*1048576, A_wp + (size_t)(l*3072 + 1024)*1024,
                                              1024,1024,1024,1024, 1.f);
    twconv_k<<<dim3(32,32), blk, 0, stream>>>(Wv, A_wp + (size_t)(l*3072 + 2048)*1024,
                                              1024,1024,1024,1024, 1.f);
  }
  twconv_k<<<dim3(32,32), blk, 0, stream>>>(Wo, WoT, 1024,1024,1024,1024, 1.f);
  twconv_k<<<dim3(88,32), blk, 0, stream>>>(Wg,  BTgu,                     1024, HID_, 1024, HIDP, 1.f);
  twconv_k<<<dim3(88,32), blk, 0, stream>>>(Wu,  BTgu + (size_t)HIDP*1024, 1024, HID_, 1024, HIDP, 1.f);
  twconv_k<<<dim3(32,88), blk, 0, stream>>>(Wdn, WdnT, HID_, 1024, HIDP, 1024, 1.f);
  gemm_t<4,1><<<dim3(8, 72), blk, 0, stream>>>(A_wp, WdecB, Wqkv, nullptr, nullptr,
                                               1024, 1024, 24, 48, 1024u*1024u);

  // ---- attention branch ----
  rmsnorm_k<<<4096, blk, 0, stream>>>(x, nw1, xn_all);
  pool_k<<<1024, blk, 0, stream>>>(xn_all,                      xn_all + (size_t)4096*1024, 10);
  pool_k<<<512,  blk, 0, stream>>>(xn_all + (size_t)4096*1024,  xn_all + (size_t)6144*1024, 9);

  gemm_t<4,1><<<dim3(24, 56), blk, 0, stream>>>(xn_all, Wqkv, QKV, nullptr, nullptr,
                                                3072, 1024, 32, 48, 3072u*1024u);
  for (int l = 0; l < 3; l++)
    vtrans_k<<<dim3(Nl[l]/32, 32, B_), blk, 0, stream>>>(QKV + (size_t)rowbase[l]*3072 + 2048,
                                                         VTa + vtoff[l], Nl[l]);
  flash_k<<<896, blk, 0, stream>>>(QKV, VTa, Ob);
  gemm_t<2,1><<<dim3(8, 112), blk, 0, stream>>>(Ob, WoT, YC, nullptr, nullptr,
                                                1024, 1024, BIG, BIG, 0u);

  u16* YC1 = YC + (size_t)4096*1024;
  u16* YC2 = YC + (size_t)6144*1024;
  zero_k<<<1, 64, 0, stream>>>(SCb);
  gram_k<<<1024, blk, 0, stream>>>(YC, YC1, YC2, SCb);
  head_k<<<1, 64, 0, stream>>>(SCb, agg, mA, mF, out + CNT);
  mix1_k<<<2048, blk, 0, stream>>>((const float4*)x, YC, YC1, YC2, SCb, (float4*)x1);

  // ---- FFN branch ----
  rmsnorm_k<<<4096, blk, 0, stream>>>(x1, nw2, xn_all);
  gemm_t<4,1><<<dim3(44, 32), blk, 0, stream>>>(xn_all, BTgu, gu, nullptr, nullptr,
                                                5632, 1024, BIG, BIG, 0u);
  silumul_k<<<2048, blk, 0, stream>>>(gu, hbuf);
  gemm_t<2,2><<<dim3(8, 64), blk, 0, stream>>>(hbuf, WdnT, out, x1, SCb,
                                               1024, HIDP, BIG, BIG, 0u);
}

// Round 5
// 505.027 us; speedup vs baseline: 1.9552x; 1.1137x over previous
//
#include <hip/hip_runtime.h>
#include <stdint.h>

// MAHA decoder block, MI355X/gfx950. Round 5: launch fusion + silu-in-GEMM.
// B=2, N=2048, D=1024, H=16(dh=64), L=3, R=2, HID=2734(->2816), fp32 I/O.

#define B_   2
#define N_   2048
#define D_   1024
#define H_   16
#define DH_  64
#define HID_ 2734
#define HIDP 2816
#define CNT  (B_*N_*D_)   // 4194304
#define LOG2E 1.4426950408889634f

typedef unsigned short u16;
typedef __attribute__((ext_vector_type(8))) short short8;
typedef __attribute__((ext_vector_type(4))) float f32x4;
typedef __attribute__((ext_vector_type(4))) uint16_t u16x4;

__device__ __forceinline__ u16 f2bf(float f) {
  uint32_t u = __builtin_bit_cast(uint32_t, f);
  u += 0x7fffu + ((u >> 16) & 1u);          // RNE
  return (u16)(u >> 16);
}
__device__ __forceinline__ float bf2f(u16 h) {
  uint32_t u = ((uint32_t)h) << 16;
  return __builtin_bit_cast(float, u);
}
__device__ __forceinline__ uint32_t pkbf(float a, float b) {
  return (uint32_t)f2bf(a) | ((uint32_t)f2bf(b) << 16);
}
__device__ __forceinline__ void gload_lds16(const void* g, void* l) {
  __builtin_amdgcn_global_load_lds(
      (const __attribute__((address_space(1))) uint32_t*)g,
      (__attribute__((address_space(3))) uint32_t*)l, 16, 0, 0);
}

// ============ batched weight prep: all fp32->bf16 transposes + Wdec convert + SC zero ====
// blocks: [0,9216) QKV weight transposes | [9216,10240) Wo | [10240,13056) Wg(gate-ilv)
// [13056,15872) Wu(up-ilv) | [15872,18688) Wdn | [18688,21760) Wdec plain convert
__global__ __launch_bounds__(256) void wprep_k(const float* __restrict__ Wdec, const float* __restrict__ Wq,
                                               const float* __restrict__ Wk, const float* __restrict__ Wv,
                                               const float* __restrict__ Wo, const float* __restrict__ Wg,
                                               const float* __restrict__ Wu, const float* __restrict__ Wdn,
                                               u16* __restrict__ A_wp, u16* __restrict__ WdecB,
                                               u16* __restrict__ WoT, u16* __restrict__ BTgu,
                                               u16* __restrict__ WdnT, float* __restrict__ SCb) {
  const int bid = blockIdx.x;
  if (bid >= 18688) {
    if (bid == 18688 && threadIdx.x < 64) SCb[threadIdx.x] = 0.f;
    int i = (bid - 18688)*1024 + threadIdx.x*4;
    float4 v = *(const float4*)(Wdec + i);
    u16x4 o; o[0]=f2bf(v.x); o[1]=f2bf(v.y); o[2]=f2bf(v.z); o[3]=f2bf(v.w);
    *(u16x4*)(WdecB + i) = o;
    return;
  }
  const float* src; u16* dst; int K, N, KP; float scale; int imode; int bx, by;
  if (bid < 9216) {
    int j = bid >> 10, t = bid & 1023; bx = t & 31; by = t >> 5;
    int l = j / 3, which = j - l*3;
    src = which==0 ? Wq + (size_t)l*1048576 : which==1 ? Wk + (size_t)l*1048576 : Wv;
    dst = A_wp + (size_t)(l*3072 + which*1024)*1024;
    K = 1024; N = 1024; KP = 1024; scale = (which==0) ? 0.125f*LOG2E : 1.f; imode = 0;
  } else if (bid < 10240) {
    int t = bid - 9216; bx = t & 31; by = t >> 5;
    src = Wo; dst = WoT; K=1024; N=1024; KP=1024; scale=1.f; imode=0;
  } else if (bid < 13056) {
    int t = bid - 10240; bx = t % 88; by = t / 88;
    src = Wg; dst = BTgu; K=1024; N=HID_; KP=1024; scale=1.f; imode=1;
  } else if (bid < 15872) {
    int t = bid - 13056; bx = t % 88; by = t / 88;
    src = Wu; dst = BTgu; K=1024; N=HID_; KP=1024; scale=1.f; imode=2;
  } else {
    int t = bid - 15872; bx = t & 31; by = t >> 5;
    src = Wdn; dst = WdnT; K=HID_; N=1024; KP=HIDP; scale=1.f; imode=0;
  }
  __shared__ float tt[32][33];
  const int tx = threadIdx.x & 31, ty = threadIdx.x >> 5;
  const int nb = bx*32, kb = by*32;
  #pragma unroll
  for (int i = 0; i < 4; i++) {
    int k = kb + ty + i*8, n = nb + tx;
    tt[ty + i*8][tx] = (k < K && n < N) ? src[(size_t)k * N + n] * scale : 0.f;
  }
  __syncthreads();
  #pragma unroll
  for (int i = 0; i < 4; i++) {
    int n = nb + ty + i*8, k = kb + tx;
    int r;
    if (imode == 0) r = n;
    else if (imode == 1) r = ((n>>4)<<5) + (n&15);
    else r = ((n>>4)<<5) + 16 + (n&15);
    dst[(size_t)r * KP + k] = f2bf(tt[tx][ty + i*8]);
  }
}

// ---------------- attention RMSNorm: 2 rows per block + fp32 pooled row ----------------
__global__ __launch_bounds__(256) void rmsA_k(const float* __restrict__ x, const float* __restrict__ w,
                                              u16* __restrict__ xn, u16* __restrict__ xp1) {
  const int j = blockIdx.x;
  const float* xr0 = x + (size_t)(2*j) * D_;
  const float* xr1 = xr0 + D_;
  float a0[4], a1[4], wv[4];
  float ss0 = 0.f, ss1 = 0.f;
  #pragma unroll
  for (int i = 0; i < 4; i++) {
    int c = threadIdx.x + i*256;
    a0[i] = xr0[c]; a1[i] = xr1[c]; wv[i] = w[c];
    ss0 += a0[i]*a0[i]; ss1 += a1[i]*a1[i];
  }
  #pragma unroll
  for (int o = 1; o < 64; o <<= 1) { ss0 += __shfl_xor(ss0, o); ss1 += __shfl_xor(ss1, o); }
  __shared__ float r0[4], r1[4];
  if ((threadIdx.x & 63) == 0) { r0[threadIdx.x >> 6] = ss0; r1[threadIdx.x >> 6] = ss1; }
  __syncthreads();
  float sc0 = rsqrtf((r0[0]+r0[1]+r0[2]+r0[3]) * (1.f/D_) + 1e-6f);
  float sc1 = rsqrtf((r1[0]+r1[1]+r1[2]+r1[3]) * (1.f/D_) + 1e-6f);
  #pragma unroll
  for (int i = 0; i < 4; i++) {
    int c = threadIdx.x + i*256;
    float xa = a0[i]*wv[i]*sc0, xb = a1[i]*wv[i]*sc1;
    xn[(size_t)(2*j)*D_ + c]     = f2bf(xa);
    xn[(size_t)(2*j)*D_ + D_ + c] = f2bf(xb);
    xp1[(size_t)j*D_ + c] = f2bf(0.5f*(xa + xb));
  }
}

// ---------------- avg-pool by 2 along seq (bf16), 4-wide; No = 1<<lg ----------------
__global__ __launch_bounds__(256) void pool_k(const u16* __restrict__ in, u16* __restrict__ out, int lg) {
  const int No = 1 << lg;
  const int total4 = B_ * No * 256;
  for (int i = blockIdx.x*256 + threadIdx.x; i < total4; i += gridDim.x*256) {
    int d4 = i & 255; int j = (i >> 8) & (No - 1); int b = i >> (8 + lg);
    size_t src = ((size_t)(b*2*No + 2*j) << 10) + d4*4;
    u16x4 a = *(const u16x4*)(in + src);
    u16x4 c = *(const u16x4*)(in + src + 1024);
    u16x4 o;
    #pragma unroll
    for (int t = 0; t < 4; t++) o[t] = f2bf(0.5f * (bf2f(a[t]) + bf2f(c[t])));
    *(u16x4*)(out + (size_t)i*4) = o;
  }
}

// ---------------- MFMA GEMM, C = A[M,K] * BT[N,K]^T; block = MT*32 x 128 ----------------
// MODE 1: bf16 store. MODE 2: fp32 out = SCp[11]*X1 + SCp[12]*acc. MODE 3: silu(gate)*up
// epilogue (BT interleaved at 16-col granularity), bf16 h store with row stride HIDP.
template<int MT, int MODE>
__global__ __launch_bounds__(256) void gemm_t(const u16* __restrict__ A, const u16* __restrict__ BT,
                                              void* __restrict__ Cv, const float* __restrict__ X1,
                                              const float* __restrict__ SCp,
                                              int N, int K, int t1, int t2, unsigned int bt_stride) {
  __shared__ __align__(16) u16 As[MT*32*32];
  __shared__ __align__(16) u16 Bs[128*32];
  const int tid = threadIdx.x;
  const int lane = tid & 63, wid = tid >> 6;
  const int quad = lane >> 4, c16 = lane & 15;
  const int y = blockIdx.y;
  const int m0 = y * (MT*32), n0 = blockIdx.x * 128;
  const int wm = wid >> 1, wn = wid & 1;
  const int level = (y >= t2) ? 2 : ((y >= t1) ? 1 : 0);
  BT += (size_t)level * bt_stride;

  f32x4 acc[MT][4];
  #pragma unroll
  for (int i = 0; i < MT; i++)
    #pragma unroll
    for (int j = 0; j < 4; j++) acc[i][j] = f32x4{0.f,0.f,0.f,0.f};

  const int srow = lane >> 2;
  const int schunk = lane & 3;
  for (int k0 = 0; k0 < K; k0 += 32) {
    #pragma unroll
    for (int t = 0; t < MT/2; t++) {
      int idx = wid*(MT/2) + t;
      int row = idx*16 + srow;
      int g = (schunk ^ ((row >> 1) & 3)) * 8;
      gload_lds16(A + (size_t)(m0+row)*K + k0 + g, As + idx*512);
    }
    #pragma unroll
    for (int t = 0; t < 2; t++) {
      int idx = wid*2 + t;
      int row = idx*16 + srow;
      int g = (schunk ^ ((row >> 1) & 3)) * 8;
      gload_lds16(BT + (size_t)(n0+row)*K + k0 + g, Bs + idx*512);
    }
    __syncthreads();
    short8 af[MT], bfr[4];
    #pragma unroll
    for (int mt = 0; mt < MT; mt++) {
      int ar = wm*(MT*16) + mt*16 + c16;
      af[mt]  = *(const short8*)(As + ar*32 + (quad ^ ((ar>>1)&3))*8);
    }
    #pragma unroll
    for (int nt = 0; nt < 4; nt++) {
      int br = wn*64 + nt*16 + c16;
      bfr[nt] = *(const short8*)(Bs + br*32 + (quad ^ ((br>>1)&3))*8);
    }
    #pragma unroll
    for (int mt = 0; mt < MT; mt++)
      #pragma unroll
      for (int nt = 0; nt < 4; nt++)
        acc[mt][nt] = __builtin_amdgcn_mfma_f32_16x16x32_bf16(af[mt], bfr[nt], acc[mt][nt], 0, 0, 0);
    __syncthreads();
  }
  if (MODE == 1) {
    u16* C = (u16*)Cv;
    #pragma unroll
    for (int mt = 0; mt < MT; mt++)
      #pragma unroll
      for (int nt = 0; nt < 4; nt++)
        #pragma unroll
        for (int r = 0; r < 4; r++) {
          int row = m0 + wm*(MT*16) + mt*16 + quad*4 + r;
          int col = n0 + wn*64 + nt*16 + c16;
          C[(size_t)row * N + col] = f2bf(acc[mt][nt][r]);
        }
  } else if (MODE == 2) {
    float* C = (float*)Cv;
    const float q0 = SCp[11], q1 = SCp[12];
    #pragma unroll
    for (int mt = 0; mt < MT; mt++)
      #pragma unroll
      for (int nt = 0; nt < 4; nt++)
        #pragma unroll
        for (int r = 0; r < 4; r++) {
          int row = m0 + wm*(MT*16) + mt*16 + quad*4 + r;
          int col = n0 + wn*64 + nt*16 + c16;
          size_t o = (size_t)row * N + col;
          C[o] = q0 * X1[o] + q1 * acc[mt][nt][r];
        }
  } else {
    u16* Hc = (u16*)Cv;
    const int hbase = (n0 >> 1) + wn*32;
    #pragma unroll
    for (int mt = 0; mt < MT; mt++)
      #pragma unroll
      for (int r = 0; r < 4; r++) {
        int row = m0 + wm*(MT*16) + mt*16 + quad*4 + r;
        #pragma unroll
        for (int pr = 0; pr < 2; pr++) {
          float g = acc[mt][2*pr][r], u = acc[mt][2*pr+1][r];
          float h = g / (1.f + __expf(-g)) * u;
          Hc[(size_t)row * HIDP + hbase + pr*16 + c16] = f2bf(h);
        }
      }
  }
}

// ---------------- merged bf16 transpose: V part of QKV -> VT [b][c][n], all levels ----
__global__ __launch_bounds__(256) void vtrans_k(const u16* __restrict__ QKV, u16* __restrict__ VTa) {
  __shared__ u16 t[32][33];
  const int bid = blockIdx.x;
  int level, tt2;
  if (bid < 4096)      { level = 0; tt2 = bid; }
  else if (bid < 6144) { level = 1; tt2 = bid - 4096; }
  else                 { level = 2; tt2 = bid - 6144; }
  const int Nl = 2048 >> level;
  const int ntiles = Nl >> 5;
  const int b = tt2 / (ntiles*32);
  const int rem = tt2 - b*(ntiles*32);
  const int c0 = (rem / ntiles) * 32;
  const int n0 = (rem - (rem / ntiles)*ntiles) * 32;
  const int rowbase = (level==0) ? 0 : (level==1) ? 4096 : 6144;
  const size_t vtoff = (level==0) ? 0 : (level==1) ? 4194304 : 6291456;
  const u16* in = QKV + (size_t)rowbase*3072 + 2048;
  u16* out = VTa + vtoff;
  const int tx = threadIdx.x & 31, ty = threadIdx.x >> 5;
  #pragma unroll
  for (int i = 0; i < 4; i++)
    t[ty + i*8][tx] = in[(size_t)(b*Nl + n0 + ty + i*8)*3072 + c0 + tx];
  __syncthreads();
  #pragma unroll
  for (int i = 0; i < 4; i++)
    out[(size_t)(b*1024 + c0 + ty + i*8)*Nl + n0 + tx] = t[tx][ty + i*8];
}

// ---------------- MFMA flash attention, all levels merged, no-max online softmax ----
__global__ __launch_bounds__(256) void flash_k(const u16* __restrict__ QKVg,
                                               const u16* __restrict__ VTg,
                                               u16* __restrict__ Og) {
  __shared__ __align__(16) u16 Kt[2][64*64];
  __shared__ __align__(16) u16 Vt[2][64*64];
  __shared__ __align__(16) u16 Ps[4][32*68];
  const int tid = threadIdx.x, lane = tid & 63, wid = tid >> 6;
  const int quad = lane >> 4, c16 = lane & 15;
  const int id = blockIdx.x;
  int qt, bh, Nl, rowbase; size_t vtoff;
  if (id < 512)      { qt = 15 - (id >> 5);            bh = id & 31;  Nl = 2048; rowbase = 0;    vtoff = 0; }
  else if (id < 768) { int t2 = id - 512; qt = 7 - (t2 >> 5); bh = t2 & 31; Nl = 1024; rowbase = 4096; vtoff = 4194304; }
  else               { int t2 = id - 768; qt = 3 - (t2 >> 5); bh = t2 & 31; Nl = 512;  rowbase = 6144; vtoff = 6291456; }
  const int b = bh >> 4, h = bh & 15;
  const u16* QK = QKVg + ((size_t)(rowbase + b*Nl)) * 3072 + h*64;
  u16* Ow = Og + ((size_t)(rowbase + b*Nl)) * 1024 + h*64;
  const u16* VT = VTg + vtoff + ((size_t)b*1024 + h*64) * (size_t)Nl;

  const int q0r = qt*128 + wid*32;
  short8 bq[2][2];
  #pragma unroll
  for (int qh = 0; qh < 2; qh++) {
    const u16* qp = QK + (size_t)(q0r + qh*16 + c16)*3072 + quad*8;
    bq[qh][0] = *(const short8*)qp;
    bq[qh][1] = *(const short8*)(qp + 32);
  }
  const int si0 = wid*2, si1 = si0 + 1;
  const int sr0 = si0*8 + (lane>>3), sr1 = si1*8 + (lane>>3);
  const int sg  = ((lane&7) ^ (lane>>3)) * 8;
  const u16* Ks0 = QK + 1024 + (size_t)sr0*3072 + sg;
  const u16* Ks1 = QK + 1024 + (size_t)sr1*3072 + sg;
  const u16* Vs0 = VT + (size_t)sr0*Nl + sg;
  const u16* Vs1 = VT + (size_t)sr1*Nl + sg;

  f32x4 oacc[2][4];
  f32x4 lacc[2];
  #pragma unroll
  for (int qh = 0; qh < 2; qh++) {
    lacc[qh] = f32x4{0.f,0.f,0.f,0.f};
    #pragma unroll
    for (int nt = 0; nt < 4; nt++) oacc[qh][nt] = f32x4{0.f,0.f,0.f,0.f};
  }

  auto stage = [&](int kt, int p) {
    const size_t ko = (size_t)kt * 64;
    gload_lds16(Ks0 + ko*3072, &Kt[p][si0*512]);
    gload_lds16(Ks1 + ko*3072, &Kt[p][si1*512]);
    gload_lds16(Vs0 + ko,      &Vt[p][si0*512]);
    gload_lds16(Vs1 + ko,      &Vt[p][si1*512]);
  };
  const int kmax_w = 2*qt + (wid >> 1);
  const int ktot   = 2*qt + 2;
  stage(0, 0);

  for (int kt = 0; kt < ktot; kt++) {
    const int p = kt & 1;
    __syncthreads();
    if (kt + 1 < ktot) stage(kt+1, p^1);
    if (kt > kmax_w) continue;

    f32x4 st[2][4];
    #pragma unroll
    for (int nt = 0; nt < 4; nt++) {
      int key = nt*16 + c16, x = key & 7;
      short8 a0 = *(const short8*)(&Kt[p][key*64 + ((quad    ) ^ x)*8]);
      short8 a1 = *(const short8*)(&Kt[p][key*64 + ((quad + 4) ^ x)*8]);
      #pragma unroll
      for (int qh = 0; qh < 2; qh++) {
        f32x4 s = f32x4{0.f,0.f,0.f,0.f};
        s = __builtin_amdgcn_mfma_f32_16x16x32_bf16(a0, bq[qh][0], s, 0, 0, 0);
        s = __builtin_amdgcn_mfma_f32_16x16x32_bf16(a1, bq[qh][1], s, 0, 0, 0);
        st[qh][nt] = s;
      }
    }
    if (kt >= 2*qt) {
      const int kb = kt*64;
      #pragma unroll
      for (int qh = 0; qh < 2; qh++) {
        const int qr = q0r + qh*16 + c16;
        #pragma unroll
        for (int nt = 0; nt < 4; nt++) {
          #pragma unroll
          for (int r = 0; r < 4; r++) {
            float e = __builtin_amdgcn_exp2f(st[qh][nt][r]);
            st[qh][nt][r] = (kb + nt*16 + quad*4 + r <= qr) ? e : 0.f;
          }
          lacc[qh] += st[qh][nt];
        }
      }
    } else {
      #pragma unroll
      for (int qh = 0; qh < 2; qh++)
        #pragma unroll
        for (int nt = 0; nt < 4; nt++) {
          #pragma unroll
          for (int r = 0; r < 4; r++) st[qh][nt][r] = __builtin_amdgcn_exp2f(st[qh][nt][r]);
          lacc[qh] += st[qh][nt];
        }
    }
    #pragma unroll
    for (int qh = 0; qh < 2; qh++) {
      const int prow = qh*16 + c16;
      #pragma unroll
      for (int nt = 0; nt < 4; nt++) {
        uint2 pk;
        pk.x = pkbf(st[qh][nt][0], st[qh][nt][1]);
        pk.y = pkbf(st[qh][nt][2], st[qh][nt][3]);
        *(uint2*)(&Ps[wid][prow*68 + nt*16 + quad*4]) = pk;
      }
    }
    short8 bp[2][2];
    #pragma unroll
    for (int qh = 0; qh < 2; qh++) {
      bp[qh][0] = *(const short8*)(&Ps[wid][(qh*16 + c16)*68 +      quad*8]);
      bp[qh][1] = *(const short8*)(&Ps[wid][(qh*16 + c16)*68 + 32 + quad*8]);
    }
    #pragma unroll
    for (int nt = 0; nt < 4; nt++) {
      int dh = nt*16 + c16, x = dh & 7;
      short8 a0 = *(const short8*)(&Vt[p][dh*64 + ((quad    ) ^ x)*8]);
      short8 a1 = *(const short8*)(&Vt[p][dh*64 + ((quad + 4) ^ x)*8]);
      #pragma unroll
      for (int qh = 0; qh < 2; qh++) {
        oacc[qh][nt] = __builtin_amdgcn_mfma_f32_16x16x32_bf16(a0, bp[qh][0], oacc[qh][nt], 0, 0, 0);
        oacc[qh][nt] = __builtin_amdgcn_mfma_f32_16x16x32_bf16(a1, bp[qh][1], oacc[qh][nt], 0, 0, 0);
      }
    }
  }
  #pragma unroll
  for (int qh = 0; qh < 2; qh++) {
    float ls = lacc[qh][0] + lacc[qh][1] + lacc[qh][2] + lacc[qh][3];
    ls += __shfl_xor(ls, 16);
    ls += __shfl_xor(ls, 32);
    const float rl = 1.f / ls;
    #pragma unroll
    for (int nt = 0; nt < 4; nt++) {
      uint2 o;
      o.x = pkbf(oacc[qh][nt][0]*rl, oacc[qh][nt][1]*rl);
      o.y = pkbf(oacc[qh][nt][2]*rl, oacc[qh][nt][3]*rl);
      *(uint2*)(Ow + (size_t)(q0r + qh*16 + c16)*1024 + nt*16 + quad*4) = o;
    }
  }
}

// ---------------- Gram matrix over repeat map (bf16 Y), 4-wide ----------------
__global__ __launch_bounds__(256) void gram_k(const u16* __restrict__ Y0, const u16* __restrict__ Y1,
                                              const u16* __restrict__ Y2, float* __restrict__ G) {
  float a[6] = {0,0,0,0,0,0};
  const int total4 = CNT/4;
  for (int i = blockIdx.x*256 + threadIdx.x; i < total4; i += gridDim.x*256) {
    int d4 = i & 255; int n = (i >> 8) & (N_-1); int b = i >> 19;
    u16x4 y0v = *(const u16x4*)(Y0 + (size_t)i*4);
    u16x4 y1v = *(const u16x4*)(Y1 + (((size_t)(b*1024 + (n>>1))) << 10) + d4*4);
    u16x4 y2v = *(const u16x4*)(Y2 + (((size_t)(b*512  + (n>>2))) << 10) + d4*4);
    #pragma unroll
    for (int t = 0; t < 4; t++) {
      float y0 = bf2f(y0v[t]), y1 = bf2f(y1v[t]), y2 = bf2f(y2v[t]);
      a[0] += y0*y0; a[1] += y0*y1; a[2] += y0*y2;
      a[3] += y1*y1; a[4] += y1*y2; a[5] += y2*y2;
    }
  }
  __shared__ float red[4][6];
  const int lane = threadIdx.x & 63, wid = threadIdx.x >> 6;
  #pragma unroll
  for (int t = 0; t < 6; t++) {
    float v = a[t];
    v += __shfl_xor(v, 1);  v += __shfl_xor(v, 2);  v += __shfl_xor(v, 4);
    v += __shfl_xor(v, 8);  v += __shfl_xor(v, 16); v += __shfl_xor(v, 32);
    a[t] = v;
  }
  if (lane == 0)
    #pragma unroll
    for (int t = 0; t < 6; t++) red[wid][t] = a[t];
  __syncthreads();
  if (threadIdx.x < 6)
    atomicAdd(&G[threadIdx.x], red[0][threadIdx.x] + red[1][threadIdx.x] +
                               red[2][threadIdx.x] + red[3][threadIdx.x]);
}

// ---------------- Nash iterations + aux loss + both Sinkhorns (scalar) ----------------
__global__ void head_k(float* SC, const float* __restrict__ agg, const float* __restrict__ mA,
                       const float* __restrict__ mF, float* __restrict__ aux_out) {
  if (threadIdx.x != 0 || blockIdx.x != 0) return;
  float G[6];
  for (int t = 0; t < 6; t++) G[t] = SC[t];
  const int gi[3][3] = {{0,1,2},{1,3,4},{2,4,5}};
  float a[3] = {agg[0], agg[1], agg[2]};
  float w[3];
  {
    float m = fmaxf(a[0], fmaxf(a[1], a[2])); float s = 0.f;
    for (int l = 0; l < 3; l++) { w[l] = expf(a[l]-m); s += w[l]; }
    for (int l = 0; l < 3; l++) w[l] /= s;
  }
  const float inv = 1.f / (float)CNT;
  for (int it = 0; it < 3; it++) {
    float q = 0.f;
    for (int l = 0; l < 3; l++) for (int m2 = 0; m2 < 3; m2++) q += w[l]*w[m2]*G[gi[l][m2]];
    float z[3];
    for (int l = 0; l < 3; l++) {
      float dot = w[0]*G[gi[l][0]] + w[1]*G[gi[l][1]] + w[2]*G[gi[l][2]];
      z[l] = a[l] - (G[gi[l][l]] - 2.f*dot + q) * inv;
    }
    float m = fmaxf(z[0], fmaxf(z[1], z[2])); float s = 0.f;
    for (int l = 0; l < 3; l++) { w[l] = expf(z[l]-m); s += w[l]; }
    for (int l = 0; l < 3; l++) w[l] /= s;
  }
  SC[6] = w[0]; SC[7] = w[1]; SC[8] = w[2];
  aux_out[0] = w[0]*logf(w[0]*3.f + 1e-9f) + w[1]*logf(w[1]*3.f + 1e-9f) + w[2]*logf(w[2]*3.f + 1e-9f);
  for (int which = 0; which < 2; which++) {
    const float* Lg = which ? mF : mA;
    float M0 = expf(Lg[0]), M1 = expf(Lg[1]), M2 = expf(Lg[2]), M3 = expf(Lg[3]);
    for (int i2 = 0; i2 < 10; i2++) {
      float r0 = M0+M1, r1 = M2+M3; M0 /= r0; M1 /= r0; M2 /= r1; M3 /= r1;
      float c0 = M0+M2, c1 = M1+M3; M0 /= c0; M2 /= c0; M1 /= c1; M3 /= c1;
    }
    SC[9 + which*2] = M0; SC[10 + which*2] = M1;
  }
}

// ---------------- fused mix1 + FFN RMSNorm: one row per block ----------------
__global__ __launch_bounds__(256) void mixrms_k(const float* __restrict__ x, const u16* __restrict__ Y0,
                                                const u16* __restrict__ Y1, const u16* __restrict__ Y2,
                                                const float* __restrict__ SC, const float* __restrict__ w2,
                                                float* __restrict__ x1, u16* __restrict__ xn2) {
  const float w0 = SC[6], w1 = SC[7], ww2 = SC[8], p0 = SC[9], p1 = SC[10];
  const int i = blockIdx.x;
  const int b = i >> 11, n = i & 2047;
  const float* xr = x + (size_t)i * D_;
  const u16* y0 = Y0 + (size_t)i * D_;
  const u16* y1 = Y1 + (size_t)(b*1024 + (n>>1)) * D_;
  const u16* y2 = Y2 + (size_t)(b*512  + (n>>2)) * D_;
  float xv[4], wv[4];
  float ss = 0.f;
  #pragma unroll
  for (int t = 0; t < 4; t++) {
    int c = threadIdx.x + t*256;
    float v = p0*xr[c] + p1*(w0*bf2f(y0[c]) + w1*bf2f(y1[c]) + ww2*bf2f(y2[c]));
    xv[t] = v; wv[t] = w2[c]; ss += v*v;
    x1[(size_t)i*D_ + c] = v;
  }
  #pragma unroll
  for (int o = 1; o < 64; o <<= 1) ss += __shfl_xor(ss, o);
  __shared__ float red[4];
  if ((threadIdx.x & 63) == 0) red[threadIdx.x >> 6] = ss;
  __syncthreads();
  float sc = rsqrtf((red[0]+red[1]+red[2]+red[3]) * (1.f/D_) + 1e-6f);
  #pragma unroll
  for (int t = 0; t < 4; t++) {
    int c = threadIdx.x + t*256;
    xn2[(size_t)i*D_ + c] = f2bf(xv[t]*wv[t]*sc);
  }
}

// ================================ host launcher ================================
extern "C" void kernel_launch(void* const* d_in, const int* in_sizes, int n_in,
                              void* d_out, int out_size, void* d_ws, size_t ws_size,
                              hipStream_t stream) {
  (void)in_sizes; (void)n_in; (void)out_size; (void)ws_size;
  const float* x    = (const float*)d_in[0];
  const float* nw1  = (const float*)d_in[1];
  const float* nw2  = (const float*)d_in[2];
  const float* Wdec = (const float*)d_in[3];
  const float* Wq   = (const float*)d_in[4];
  const float* Wk   = (const float*)d_in[5];
  const float* Wv   = (const float*)d_in[6];
  const float* Wo   = (const float*)d_in[7];
  const float* agg  = (const float*)d_in[8];
  const float* Wg   = (const float*)d_in[9];
  const float* Wu   = (const float*)d_in[10];
  const float* Wdn  = (const float*)d_in[11];
  const float* mA   = (const float*)d_in[12];
  const float* mF   = (const float*)d_in[13];
  float* out = (float*)d_out;

  char* ws = (char*)d_ws;
  size_t off = 0;
  auto take = [&](size_t b) { size_t r = off; off += (b + 255) & ~(size_t)255; return r; };

  u16* A_wp  = (u16*)(ws + take((size_t)9216*1024*2));
  u16* WdecB = (u16*)(ws + take((size_t)3*1024*1024*2));
  u16* Wqkv  = (u16*)(ws + take((size_t)9216*1024*2));
  u16* BTgu  = (u16*)(ws + take((size_t)5632*1024*2));   // gate/up 16-col interleaved
  u16* WdnT  = (u16*)(ws + take((size_t)HIDP*1024*2));
  u16* WoT   = (u16*)(ws + take((size_t)1024*1024*2));
  u16* xn_all = (u16*)(ws + take((size_t)7168*1024*2));
  float* x1  = (float*)(ws + take((size_t)CNT*4));
  float* SCb = (float*)(ws + take(256));
  char*  big = ws + take(88080384);
  // attention phase
  u16*   QKV   = (u16*)big;                              // [7168, 3072] bf16
  u16*   VTa   = (u16*)(big + 44040192);                 // per-level [b][1024][Nl]
  u16*   Ob    = (u16*)(big + 58720256);                 // [7168, 1024] bf16
  u16*   YC    = (u16*)(big + 73400320);                 // [7168, 1024] bf16
  // FFN phase alias (attention working set dead by then; YC region untouched)
  u16*   hbuf  = (u16*)big;                              // [4096, 2816] bf16

  dim3 blk(256);
  const int BIG = 1 << 30;

  // ---- 1: all weight prep in one launch (+ SCb zero) ----
  wprep_k<<<21760, blk, 0, stream>>>(Wdec, Wq, Wk, Wv, Wo, Wg, Wu, Wdn,
                                     A_wp, WdecB, WoT, BTgu, WdnT, SCb);
  // ---- 2: fused QKV weights: F_l^T = [Wq|Wk|Wv]_l^T x Wdec_l^T ----
  gemm_t<4,1><<<dim3(8, 72), blk, 0, stream>>>(A_wp, WdecB, Wqkv, nullptr, nullptr,
                                               1024, 1024, 24, 48, 1024u*1024u);
  // ---- 3-4: attention RMSNorm (+pool1 fused), pool2 ----
  rmsA_k<<<2048, blk, 0, stream>>>(x, nw1, xn_all, xn_all + (size_t)4096*1024);
  pool_k<<<512, blk, 0, stream>>>(xn_all + (size_t)4096*1024, xn_all + (size_t)6144*1024, 9);
  // ---- 5: QKV GEMM (per-level weight select) ----
  gemm_t<4,1><<<dim3(24, 56), blk, 0, stream>>>(xn_all, Wqkv, QKV, nullptr, nullptr,
                                                3072, 1024, 32, 48, 3072u*1024u);
  // ---- 6: V transpose (all levels) ----
  vtrans_k<<<7168, blk, 0, stream>>>(QKV, VTa);
  // ---- 7: flash attention (all levels) ----
  flash_k<<<896, blk, 0, stream>>>(QKV, VTa, Ob);
  // ---- 8: output projection -> YC (bf16) ----
  gemm_t<2,1><<<dim3(8, 112), blk, 0, stream>>>(Ob, WoT, YC, nullptr, nullptr,
                                                1024, 1024, BIG, BIG, 0u);
  // ---- 9-10: Nash via Gram + scalar head ----
  u16* YC1 = YC + (size_t)4096*1024;
  u16* YC2 = YC + (size_t)6144*1024;
  gram_k<<<1024, blk, 0, stream>>>(YC, YC1, YC2, SCb);
  head_k<<<1, 64, 0, stream>>>(SCb, agg, mA, mF, out + CNT);
  // ---- 11: mix1 + FFN RMSNorm fused ----
  mixrms_k<<<4096, blk, 0, stream>>>(x, YC, YC1, YC2, SCb, nw2, x1, xn_all);
  // ---- 12: gate/up GEMM with fused silu*mul epilogue ----
  gemm_t<4,3><<<dim3(44, 32), blk, 0, stream>>>(xn_all, BTgu, hbuf, nullptr, nullptr,
                                                5632, 1024, BIG, BIG, 0u);
  // ---- 13: down GEMM with fused final residual mix ----
  gemm_t<2,2><<<dim3(8, 64), blk, 0, stream>>>(hbuf, WdnT, out, x1, SCb,
                                               1024, HIDP, BIG, BIG, 0u);
}